// Round 3
// baseline (864.627 us; speedup 1.0000x reference)
//
#include <hip/hip_runtime.h>
#include <hip/hip_bf16.h>

// Problem constants (match reference)
constexpr int B = 8192;
constexpr int G = 1024;
constexpr int E = 256;
constexpr int K = 2048;
constexpr float P_NULL = 0.1f;
constexpr int N_STEP = 4;

typedef unsigned short u16;
typedef short bf16x8 __attribute__((ext_vector_type(8)));
typedef float f32x4 __attribute__((ext_vector_type(4)));

// raw-sync primitives (step_kernel pipelining)
#define S_BARRIER __builtin_amdgcn_s_barrier()
#define SCHED0 __builtin_amdgcn_sched_barrier(0)
#define WAIT_VM0 asm volatile("s_waitcnt vmcnt(0)" ::: "memory")
#define WAIT_LGKM0 asm volatile("s_waitcnt lgkmcnt(0)" ::: "memory")

// ---------------------------------------------------------------------------
// bf16 <-> f32 (RNE)
// ---------------------------------------------------------------------------
__device__ inline u16 f2bf(float f) {
    union { float f; uint32_t u; } cv;
    cv.f = f;
    const uint32_t u = cv.u;
    return (u16)((u + 0x7fffu + ((u >> 16) & 1u)) >> 16);
}
__device__ inline float bf2f(u16 h) {
    union { uint32_t u; float f; } cv;
    cv.u = ((uint32_t)h) << 16;
    return cv.f;
}
__device__ inline uint4 pack8(const float* v) {
    uint4 u;
    u.x = (uint32_t)f2bf(v[0]) | ((uint32_t)f2bf(v[1]) << 16);
    u.y = (uint32_t)f2bf(v[2]) | ((uint32_t)f2bf(v[3]) << 16);
    u.z = (uint32_t)f2bf(v[4]) | ((uint32_t)f2bf(v[5]) << 16);
    u.w = (uint32_t)f2bf(v[6]) | ((uint32_t)f2bf(v[7]) << 16);
    return u;
}

// async global->LDS, 16B per lane (LDS dest is lane-linear; global src is
// per-lane and may be permuted -> XOR-swizzle is applied on the GLOBAL side)
typedef __attribute__((address_space(1))) const void* gaddr_t;
typedef __attribute__((address_space(3))) void* laddr_t;
__device__ inline void gload_lds16(const void* g, void* l) {
    __builtin_amdgcn_global_load_lds((gaddr_t)g, (laddr_t)l, 16, 0, 0);
}

// XCD-aware tile swizzle (requires gridDim.y % 8 == 0)
__device__ inline void swizzle_tiles(int& tr, int& tc) {
    const int cx = gridDim.x, cy = gridDim.y;
    const int id = blockIdx.y * cx + blockIdx.x;
    const int k = id & 7;
    const int q = id >> 3;
    tr = k * (cy >> 3) + q / cx;
    tc = q % cx;
}

// ---------------------------------------------------------------------------
// Reduction helpers (256-thread blocks, wave64)
// ---------------------------------------------------------------------------
__device__ inline float wave_sum(float v) {
#pragma unroll
    for (int off = 32; off > 0; off >>= 1) v += __shfl_down(v, off, 64);
    return v;
}
__device__ inline float block_sum256(float v, float* sm) {
    v = wave_sum(v);
    const int w = threadIdx.x >> 6;
    if ((threadIdx.x & 63) == 0) sm[w] = v;
    __syncthreads();
    const float r = sm[0] + sm[1] + sm[2] + sm[3];
    __syncthreads();
    return r;
}

// ---------------------------------------------------------------------------
// f32 -> bf16 flat convert, 8 elems/thread
// ---------------------------------------------------------------------------
__global__ __launch_bounds__(256) void f2bf_kernel(
    const float* __restrict__ in, u16* __restrict__ out, int n) {
    const int i = (blockIdx.x * 256 + threadIdx.x) * 8;
    if (i + 7 >= n) {
        for (int j = i; j < n; ++j) out[j] = f2bf(in[j]);
        return;
    }
    const float4 a = *(const float4*)(in + i);
    const float4 b = *(const float4*)(in + i + 4);
    float v[8] = {a.x, a.y, a.z, a.w, b.x, b.y, b.z, b.w};
    *(uint4*)(out + i) = pack8(v);
}

// ---------------------------------------------------------------------------
// Fused prep: f32 (R,C) -> bf16 (R,C) copy + bf16 (C,R) transpose +
// csq[c] += (1/R) sum_r v^2.  grid (C/32, R/32), block 256.
// ---------------------------------------------------------------------------
__global__ __launch_bounds__(256) void prep_kernel(
    const float* __restrict__ in, u16* __restrict__ outN,
    u16* __restrict__ outT, float* __restrict__ csq, int R, int C,
    float inv_R) {
    __shared__ float tile[32][33];
    __shared__ float sred[8][32];
    const int bx = blockIdx.x * 32, by = blockIdx.y * 32;
    const int x = threadIdx.x & 31, y0 = threadIdx.x >> 5;
    float s = 0.f;
#pragma unroll
    for (int yy = 0; yy < 32; yy += 8) {
        const float v = in[(size_t)(by + y0 + yy) * C + bx + x];
        tile[y0 + yy][x] = v;
        outN[(size_t)(by + y0 + yy) * C + bx + x] = f2bf(v);
        s = fmaf(v, v, s);
    }
    sred[y0][x] = s;
    __syncthreads();
#pragma unroll
    for (int yy = 0; yy < 32; yy += 8)
        outT[(size_t)(bx + y0 + yy) * R + by + x] = f2bf(tile[x][y0 + yy]);
    if (y0 == 0) {
        float t = 0.f;
#pragma unroll
        for (int k2 = 0; k2 < 8; ++k2) t += sred[k2][x];
        atomicAdd(csq + bx + x, t * inv_R);
    }
}

// ---------------------------------------------------------------------------
// MFMA bf16 GEMM, 128x64 tile (R11, kept for encode/decode):
//   EPI_U: u = exp(alpha*acc - bias[col]) -> bf16 C; Saux[row] += row-sum
//   EPI_W: kept for reference (unused in this round)
// ---------------------------------------------------------------------------
enum { EPI_U = 0, EPI_W = 1 };

template <int EPI>
__global__ __launch_bounds__(256) void mfma_n64_kernel(
    const u16* __restrict__ A, const u16* __restrict__ Bm,
    u16* __restrict__ C, const float* __restrict__ bias,
    const u16* __restrict__ Paux, float* __restrict__ Saux,
    int M, int N, int Kd, float alpha) {
    __shared__ u16 smem[12288];  // As 8192 (128x64) | Bs 4096 (64x64)
    u16* As = smem;
    u16* Bs = smem + 8192;
    const int tid = threadIdx.x;
    int btr, btc;
    swizzle_tiles(btr, btc);
    const int row0 = btr * 128, col0 = btc * 64;
    const int lane = tid & 63, wave = tid >> 6;
    const int wr = wave * 32;
    const int tx = lane & 15, quad = lane >> 4;
    const int txl = tx & 7;

    f32x4 acc[2][4] = {};

    for (int k0 = 0; k0 < Kd; k0 += 64) {
#pragma unroll
        for (int l = 0; l < 4; ++l) {
            const int lin = l * 2048 + tid * 8;
            const int r = lin >> 6;
            const int c = (((lin >> 3) & 7) ^ (r & 7)) * 8;  // XOR-swizzled src
            gload_lds16(A + (size_t)(row0 + r) * Kd + k0 + c, &As[lin]);
        }
#pragma unroll
        for (int l = 0; l < 2; ++l) {
            const int lin = l * 2048 + tid * 8;
            const int r = lin >> 6;
            const int c = (((lin >> 3) & 7) ^ (r & 7)) * 8;
            gload_lds16(Bm + (size_t)(col0 + r) * Kd + k0 + c, &Bs[lin]);
        }
        __syncthreads();
#pragma unroll
        for (int ks = 0; ks < 2; ++ks) {
            bf16x8 af[2], bfr[4];
            const int gsw = ((ks * 4 + quad) ^ txl) * 8;
#pragma unroll
            for (int i = 0; i < 2; ++i)
                af[i] = *(const bf16x8*)&As[(wr + i * 16 + tx) * 64 + gsw];
#pragma unroll
            for (int j = 0; j < 4; ++j)
                bfr[j] = *(const bf16x8*)&Bs[(j * 16 + tx) * 64 + gsw];
#pragma unroll
            for (int i = 0; i < 2; ++i)
#pragma unroll
                for (int j = 0; j < 4; ++j)
                    acc[i][j] = __builtin_amdgcn_mfma_f32_16x16x32_bf16(
                        af[i], bfr[j], acc[i][j], 0, 0, 0);
        }
        __syncthreads();
    }

    if (EPI == EPI_W) {
#pragma unroll
        for (int l = 0; l < 4; ++l) {
            const int lin = l * 2048 + tid * 8;
            const int r = lin >> 6;
            const int g = (lin >> 3) & 7;
            const int c = (g ^ (r & 7)) << 3;
            gload_lds16(Paux + (size_t)(row0 + r) * N + col0 + c, &smem[lin]);
        }
    }
    __syncthreads();

#pragma unroll
    for (int i = 0; i < 2; ++i) {
        float srow[4] = {0.f, 0.f, 0.f, 0.f};
#pragma unroll
        for (int j = 0; j < 4; ++j) {
            const int pcol = j * 16 + tx;
            const float cb = bias[col0 + pcol];
#pragma unroll
            for (int r = 0; r < 4; ++r) {
                const int prow = wr + i * 16 + quad * 4 + r;
                const int paddr = prow * 64 +
                    (((pcol >> 3) ^ (prow & 7)) << 3) + (pcol & 7);
                float v = __expf(fmaf(acc[i][j][r], alpha, -cb));
                if (EPI == EPI_W) v *= bf2f(smem[paddr]);
                srow[r] += v;
                smem[paddr] = f2bf(v);
            }
        }
#pragma unroll
        for (int r = 0; r < 4; ++r) {
            float s = srow[r];
            s += __shfl_xor(s, 1, 64);
            s += __shfl_xor(s, 2, 64);
            s += __shfl_xor(s, 4, 64);
            s += __shfl_xor(s, 8, 64);
            if (tx == 0)
                atomicAdd(&Saux[row0 + wr + i * 16 + quad * 4 + r], s);
        }
    }
    __syncthreads();

    const int rr = tid >> 1, hs = tid & 1;
#pragma unroll
    for (int u = 0; u < 4; ++u) {
        const int gl = hs * 4 + u;
        const int pg = gl ^ (rr & 7);
        *(uint4*)(C + (size_t)(row0 + rr) * N + col0 + gl * 8) =
            *(const uint4*)&smem[rr * 64 + pg * 8];
    }
}

// ---------------------------------------------------------------------------
// MFMA bf16 GEMM, 64x64 tile, for z0 = (e @ xb^T) / S_enc[row].
// ---------------------------------------------------------------------------
__global__ __launch_bounds__(256) void mfma_z64_kernel(
    const u16* __restrict__ A, const u16* __restrict__ Bm,
    u16* __restrict__ C, const float* __restrict__ Srow,
    int M, int N, int Kd) {
    __shared__ u16 As[64 * 64];
    __shared__ u16 Bs[64 * 64];
    const int tid = threadIdx.x;
    int btr, btc;
    swizzle_tiles(btr, btc);
    const int row0 = btr * 64, col0 = btc * 64;
    const int lane = tid & 63, wave = tid >> 6;
    const int wr = (wave >> 1) * 32, wc = (wave & 1) * 32;
    const int tx = lane & 15, quad = lane >> 4;
    const int txl = tx & 7;

    f32x4 acc[2][2] = {};

    for (int k0 = 0; k0 < Kd; k0 += 64) {
#pragma unroll
        for (int l = 0; l < 2; ++l) {
            const int lin = l * 2048 + tid * 8;
            const int r = lin >> 6;
            const int c = (((lin >> 3) & 7) ^ (r & 7)) * 8;
            gload_lds16(A + (size_t)(row0 + r) * Kd + k0 + c, &As[lin]);
        }
#pragma unroll
        for (int l = 0; l < 2; ++l) {
            const int lin = l * 2048 + tid * 8;
            const int r = lin >> 6;
            const int c = (((lin >> 3) & 7) ^ (r & 7)) * 8;
            gload_lds16(Bm + (size_t)(col0 + r) * Kd + k0 + c, &Bs[lin]);
        }
        __syncthreads();
#pragma unroll
        for (int ks = 0; ks < 2; ++ks) {
            bf16x8 af[2], bfr[2];
            const int gsw = ((ks * 4 + quad) ^ txl) * 8;
#pragma unroll
            for (int i = 0; i < 2; ++i)
                af[i] = *(const bf16x8*)&As[(wr + i * 16 + tx) * 64 + gsw];
#pragma unroll
            for (int j = 0; j < 2; ++j)
                bfr[j] = *(const bf16x8*)&Bs[(wc + j * 16 + tx) * 64 + gsw];
#pragma unroll
            for (int i = 0; i < 2; ++i)
#pragma unroll
                for (int j = 0; j < 2; ++j)
                    acc[i][j] = __builtin_amdgcn_mfma_f32_16x16x32_bf16(
                        af[i], bfr[j], acc[i][j], 0, 0, 0);
        }
        __syncthreads();
    }

#pragma unroll
    for (int i = 0; i < 2; ++i)
#pragma unroll
        for (int r = 0; r < 4; ++r) {
            const int row = row0 + wr + i * 16 + quad * 4 + r;
            const float sc = Srow ? (1.0f / Srow[row]) : 1.0f;
#pragma unroll
            for (int j = 0; j < 2; ++j) {
                const int col = col0 + wc + j * 16 + tx;
                C[(size_t)row * N + col] = f2bf(acc[i][j][r] * sc);
            }
        }
}

// ---------------------------------------------------------------------------
// FUSED loop-step kernel, R3: register-direct operand loads.
// R0-R2 post-mortem: time pinned at ~62-65us across schedule changes AND a
// 2x L2-traffic cut -> bottleneck is the per-CU LDS port: 72KB/chunk staged
// via global_load_lds + ~110KB/chunk ds_read re-reads ~= 2,300 cy/chunk of
// port time, stacked with unoverlapped e HBM latency. Fix: load xbT/xb MFMA
// B-fragments DIRECTLY global->register (L2-resident broadcast data, VMEM
// path at 6% util). LDS kept only for the unavoidable transposes (e, w).
//   - bfr (t-part B-frags): register double-buffer across chunks (unroll-2,
//     statically named bufA/bufB; compiler emits counted vmcnt waits)
//   - b2 (z-part B-frags): loaded at chunk top, used after B1 (~600cy cover)
//   - e chunk: coalesced uint4 reg load at top, ds_write after z-part
//     (~1,200cy cover), dbuf es in LDS; epilogue reads as before
//   - NO vmcnt drains in the loop; 2 barriers/chunk are lgkm-only
// 64 rows/block, 512 thr (8 waves = 2/SIMD), 128 blocks. LDS ~57KB.
// ---------------------------------------------------------------------------
__global__ __launch_bounds__(512, 2) void step_kernel(
    u16* __restrict__ Z,            // (B,E) in/out
    const u16* __restrict__ XbT,    // (K,E)
    const u16* __restrict__ Xb,     // (E,K)
    const u16* __restrict__ Ebf,    // (B,K) unnormalized encode weights
    const float* __restrict__ c2b) {
    __shared__ u16 zbuf[64 * 256];   // 32KB: z band, subtile-64 layout
    __shared__ u16 es[2][64 * 64];   // 2x8KB e chunk: [half][32r][64k]
    __shared__ u16 ws[64 * 64];      // 8KB w transit: [half][32r][64k]
    const int tid = threadIdx.x;
    const int lane = tid & 63, wave = tid >> 6;
    const int wh = wave >> 2, wk = wave & 3;   // row-half, kcol-quarter
    const int tx = lane & 15, quad = lane >> 4;
    const int row0 = blockIdx.x * 64;
    const float ascale = 2.0f / (float)E;
    const int kcol = wk * 16 + tx;             // k-col within chunk (0..63)
    const int hbase = wh * 2048;               // half offset in es/ws
    const int erow_ = tid >> 3;                // e stage: row (0..63)
    const int ec8_ = tid & 7;                  // e stage: col-group
    const int ewaddr = erow_ * 64 + ((ec8_ ^ (erow_ & 7)) << 3);

    // ---- prologue: stage z band + e chunk 0 (swizzled gload; drain once) ----
#pragma unroll
    for (int l = 0; l < 4; ++l) {
        const int lin = l * 4096 + tid * 8;
        const int q = lin >> 12, r = (lin >> 6) & 63, g = (lin >> 3) & 7;
        gload_lds16(Z + (size_t)(row0 + r) * E + q * 64 + ((g ^ (r & 7)) << 3),
                    &zbuf[lin]);
    }
    {
        const int lin = tid * 8;
        const int r = lin >> 6, g = (lin >> 3) & 7;
        gload_lds16(Ebf + (size_t)(row0 + r) * K + ((g ^ (r & 7)) << 3),
                    &es[0][lin]);
    }
    WAIT_VM0;
    SCHED0;
    S_BARRIER;
    SCHED0;

    // z A-frags from zbuf: af[i][s], s covers E=256 (zbuf untouched in loop)
    bf16x8 af[2][8];
#pragma unroll
    for (int i = 0; i < 2; ++i) {
        const int row = wh * 32 + i * 16 + tx;
#pragma unroll
        for (int s = 0; s < 8; ++s) {
            const int g = ((s & 1) * 4 + quad) ^ (row & 7);
            af[i][s] = *(const bf16x8*)&zbuf[(s >> 1) * 4096 + row * 64 + (g << 3)];
        }
    }

    // chunk-0 bfr + cb into the 'A' register buffer
    bf16x8 bfrA[8], bfrB[8];
    float cbA, cbB;
#pragma unroll
    for (int s = 0; s < 8; ++s)
        bfrA[s] = *(const bf16x8*)&XbT[(size_t)kcol * E + s * 32 + quad * 8];
    cbA = c2b[kcol];

    f32x4 acc2[2][4] = {};            // z' accumulator
    float srow[2][4] = {};            // Sw partials (C-layout rows)

    // ---- main loop: unroll-2 so register pipelines stay statically named ---
#define STEP_CHUNK(KC, BFC, BFN, CBC, CBN)                                     \
    {                                                                          \
        const int p = (KC)&1;                                                  \
        uint4 ereg = {0, 0, 0, 0};                                             \
        if ((KC) < 31) {                                                       \
            const int kn0 = ((KC) + 1) * 64;                                   \
            ereg = *(const uint4*)&Ebf[(size_t)(row0 + erow_) * K + kn0 +      \
                                       ec8_ * 8];                              \
            CBN = c2b[kn0 + kcol];                                             \
            _Pragma("unroll") for (int s = 0; s < 8; ++s)                      \
                BFN[s] = *(const bf16x8*)&XbT[(size_t)(kn0 + kcol) * E +       \
                                              s * 32 + quad * 8];              \
        }                                                                      \
        bf16x8 b2_[2][4];                                                      \
        _Pragma("unroll") for (int kk = 0; kk < 2; ++kk)                       \
            _Pragma("unroll") for (int f = 0; f < 4; ++f)                      \
                b2_[kk][f] = *(const bf16x8*)&Xb[(size_t)(wk * 64 + f * 16 +   \
                                                          tx) * K +            \
                                                 (KC)*64 + kk * 32 +           \
                                                 quad * 8];                    \
        /* t-part: ta = z(rows of half wh) @ xbT(k-col = kcol) */              \
        f32x4 ta[2][2] = {};                                                   \
        _Pragma("unroll") for (int s = 0; s < 8; ++s)                          \
            _Pragma("unroll") for (int i = 0; i < 2; ++i)                      \
                ta[i][s & 1] = __builtin_amdgcn_mfma_f32_16x16x32_bf16(        \
                    af[i][s], BFC[s], ta[i][s & 1], 0, 0, 0);                  \
        /* epilogue: w = e * exp(t*ascale - cb) -> ws; Sw partial */           \
        _Pragma("unroll") for (int i = 0; i < 2; ++i)                          \
            _Pragma("unroll") for (int r = 0; r < 4; ++r) {                    \
                const int prow = i * 16 + quad * 4 + r;                        \
                const int paddr = hbase + prow * 64 +                          \
                                  (((kcol >> 3) ^ (prow & 7)) << 3) +          \
                                  (kcol & 7);                                  \
                const float ev = bf2f(es[p][paddr]);                           \
                const float tv = ta[i][0][r] + ta[i][1][r];                    \
                const float wv = ev * __expf(fmaf(tv, ascale, -(CBC)));        \
                srow[i][r] += wv;                                              \
                ws[paddr] = f2bf(wv);                                          \
            }                                                                  \
        /* B1: ws visible (lgkm only; reg loads stay in flight) */             \
        WAIT_LGKM0;                                                            \
        S_BARRIER;                                                             \
        SCHED0;                                                                \
        /* z-part: acc2 += w(half wh, 64k) @ xb^T(e = wk*64..) */              \
        _Pragma("unroll") for (int kk = 0; kk < 2; ++kk) {                     \
            bf16x8 a2[2];                                                      \
            _Pragma("unroll") for (int i = 0; i < 2; ++i) {                    \
                const int row = i * 16 + tx;                                   \
                a2[i] = *(const bf16x8*)&ws[hbase + row * 64 +                 \
                                            ((((kk * 4 + quad) ^               \
                                               (row & 7))) << 3)];             \
            }                                                                  \
            _Pragma("unroll") for (int f = 0; f < 4; ++f)                      \
                _Pragma("unroll") for (int i = 0; i < 2; ++i)                  \
                    acc2[i][f] = __builtin_amdgcn_mfma_f32_16x16x32_bf16(      \
                        a2[i], b2_[kk][f], acc2[i][f], 0, 0, 0);               \
        }                                                                      \
        /* stage e(KC+1) to LDS (vmcnt wait inserted here by compiler) */      \
        if ((KC) < 31) *(uint4*)&es[p ^ 1][ewaddr] = ereg;                     \
        /* B2: es write visible; all ws/es[p] reads done */                    \
        WAIT_LGKM0;                                                            \
        S_BARRIER;                                                             \
        SCHED0;                                                                \
    }

    for (int kc2 = 0; kc2 < 16; ++kc2) {
        STEP_CHUNK(kc2 * 2, bfrA, bfrB, cbA, cbB);
        STEP_CHUNK(kc2 * 2 + 1, bfrB, bfrA, cbB, cbA);
    }
#undef STEP_CHUNK

    // ---- Sw: reduce over tx lanes, then across each half's 4 waves ----
    float* redS = (float*)ws;  // ws is dead after the loop; overlay (1KB)
#pragma unroll
    for (int i = 0; i < 2; ++i)
#pragma unroll
        for (int r = 0; r < 4; ++r) {
            float s = srow[i][r];
            s += __shfl_xor(s, 1, 64);
            s += __shfl_xor(s, 2, 64);
            s += __shfl_xor(s, 4, 64);
            s += __shfl_xor(s, 8, 64);
            if (tx == 0) redS[wave * 32 + i * 16 + quad * 4 + r] = s;
        }
    __syncthreads();
    float invS[2][4];
#pragma unroll
    for (int i = 0; i < 2; ++i)
#pragma unroll
        for (int r = 0; r < 4; ++r) {
            const int row = i * 16 + quad * 4 + r;
            invS[i][r] = 1.0f / (redS[(wh * 4 + 0) * 32 + row] +
                                 redS[(wh * 4 + 1) * 32 + row] +
                                 redS[(wh * 4 + 2) * 32 + row] +
                                 redS[(wh * 4 + 3) * 32 + row]);
        }

    // ---- write z' = acc2/Sw back through LDS (subtile-64), coalesced ----
#pragma unroll
    for (int i = 0; i < 2; ++i)
#pragma unroll
        for (int f = 0; f < 4; ++f)
#pragma unroll
            for (int r = 0; r < 4; ++r) {
                const int row = wh * 32 + i * 16 + quad * 4 + r;
                const int e = wk * 64 + f * 16 + tx;
                const int addr = (e >> 6) * 4096 + row * 64 +
                    ((((e >> 3) & 7) ^ (row & 7)) << 3) + (e & 7);
                zbuf[addr] = f2bf(acc2[i][f][r] * invS[i][r]);
            }
    __syncthreads();
#pragma unroll
    for (int l = 0; l < 4; ++l) {
        const int lin = l * 4096 + tid * 8;
        const int q = lin >> 12, r = (lin >> 6) & 63, g = (lin >> 3) & 7;
        *(uint4*)(Z + (size_t)(row0 + r) * E + q * 64 + g * 8) =
            *(const uint4*)&zbuf[q * 4096 + r * 64 + ((g ^ (r & 7)) << 3)];
    }
}

// ---------------------------------------------------------------------------
// MFMA bf16 GEMM (128x128 tile) with fused MSE-loss epilogue:
// D = P_NULL*exp(x2[row]) + S0[row];
// loss[row] += (1/N)*sum_col (acc/D - X[row,col])^2
// ---------------------------------------------------------------------------
__global__ __launch_bounds__(256) void mfma_loss_kernel(
    const u16* __restrict__ A, const u16* __restrict__ Bm,
    float* __restrict__ loss, const float* __restrict__ x2,
    const float* __restrict__ X, const float* __restrict__ S0,
    int M, int N, int Kd) {
    __shared__ u16 As[128 * 64];
    __shared__ u16 Bs[128 * 64];
    const int tid = threadIdx.x;
    int btr, btc;
    swizzle_tiles(btr, btc);
    const int row0 = btr * 128, col0 = btc * 128;
    const int lane = tid & 63, wave = tid >> 6;
    const int wr = (wave >> 1) * 64, wc = (wave & 1) * 64;
    const int tx = lane & 15, quad = lane >> 4;
    const int txl = tx & 7;

    f32x4 acc[4][4] = {};

    for (int k0 = 0; k0 < Kd; k0 += 64) {
#pragma unroll
        for (int l = 0; l < 4; ++l) {
            const int lin = l * 2048 + tid * 8;
            const int r = lin >> 6;
            const int c = (((lin >> 3) & 7) ^ (r & 7)) * 8;
            gload_lds16(A + (size_t)(row0 + r) * Kd + k0 + c, &As[lin]);
        }
#pragma unroll
        for (int l = 0; l < 4; ++l) {
            const int lin = l * 2048 + tid * 8;
            const int r = lin >> 6;
            const int c = (((lin >> 3) & 7) ^ (r & 7)) * 8;
            gload_lds16(Bm + (size_t)(col0 + r) * Kd + k0 + c, &Bs[lin]);
        }
        __syncthreads();
#pragma unroll
        for (int ks = 0; ks < 2; ++ks) {
            bf16x8 af[4], bfr[4];
            const int gsw = ((ks * 4 + quad) ^ txl) * 8;
#pragma unroll
            for (int i = 0; i < 4; ++i)
                af[i] = *(const bf16x8*)&As[(wr + i * 16 + tx) * 64 + gsw];
#pragma unroll
            for (int j = 0; j < 4; ++j)
                bfr[j] = *(const bf16x8*)&Bs[(wc + j * 16 + tx) * 64 + gsw];
#pragma unroll
            for (int i = 0; i < 4; ++i)
#pragma unroll
                for (int j = 0; j < 4; ++j)
                    acc[i][j] = __builtin_amdgcn_mfma_f32_16x16x32_bf16(
                        af[i], bfr[j], acc[i][j], 0, 0, 0);
        }
        __syncthreads();
    }

    const float inv_n = 1.0f / (float)N;
#pragma unroll
    for (int i = 0; i < 4; ++i) {
#pragma unroll
        for (int r = 0; r < 4; ++r) {
            const int row = row0 + wr + i * 16 + quad * 4 + r;
            const float D = P_NULL * __expf(x2[row]) + S0[row];
            const float invD = 1.0f / D;
            float s = 0.f;
#pragma unroll
            for (int j = 0; j < 4; ++j) {
                const int col = col0 + wc + j * 16 + tx;
                const float d = acc[i][j][r] * invD - X[(size_t)row * N + col];
                s = fmaf(d, d, s);
            }
            s += __shfl_xor(s, 1, 64);
            s += __shfl_xor(s, 2, 64);
            s += __shfl_xor(s, 4, 64);
            s += __shfl_xor(s, 8, 64);
            if (tx == 0) atomicAdd(&loss[row], s * inv_n);
        }
    }
}

// ---------------------------------------------------------------------------
// Row mean of squares of Z (B,E) bf16: x2[row] = mean(Z[row,:]^2)
// ---------------------------------------------------------------------------
__global__ __launch_bounds__(256) void rowmeansq_bf_kernel(
    const u16* __restrict__ Z, float* __restrict__ out) {
    __shared__ float sm[4];
    const float v = bf2f(Z[(size_t)blockIdx.x * E + threadIdx.x]);
    const float s = block_sum256(v * v, sm);
    if (threadIdx.x == 0) out[blockIdx.x] = s * (1.0f / (float)E);
}

// ---------------------------------------------------------------------------
extern "C" void kernel_launch(void* const* d_in, const int* in_sizes, int n_in,
                              void* d_out, int out_size, void* d_ws, size_t ws_size,
                              hipStream_t stream) {
    const float* images = (const float*)d_in[0];  // (B,G)
    const float* xa     = (const float*)d_in[1];  // (G,K)
    const float* xb     = (const float*)d_in[2];  // (E,K)
    float* out = (float*)d_out;                   // (B,)

    // workspace carve-up (u16 elements, all regions 16B-aligned)
    u16* img_bf = (u16*)d_ws;                      // B*G
    u16* xa_bf  = img_bf + (size_t)B * G;          // G*K
    u16* xaT_bf = xa_bf + (size_t)G * K;           // K*G
    u16* xb_bf  = xaT_bf + (size_t)K * G;          // E*K
    u16* xbT_bf = xb_bf + (size_t)E * K;           // K*E
    u16* e_bf   = xbT_bf + (size_t)K * E;          // B*K (unnormalized enc e)
    u16* wu_bf  = e_bf + (size_t)B * K;            // B*K (decode u)
    u16* z_bf   = wu_bf + (size_t)B * K;           // B*E
    float* c2a  = (float*)(z_bf + (size_t)B * E);  // K   --+ one memset
    float* c2b  = c2a + K;                         // K     |
    float* Svec = c2b + K;                         // 2*B --+ (S_enc, S0)
    float* x2z  = Svec + 2 * B;                    // B (fully written)

    (void)hipMemsetAsync(d_out, 0, (size_t)B * sizeof(float), stream);
    (void)hipMemsetAsync(c2a, 0, (size_t)(2 * K + 2 * B) * sizeof(float), stream);

    // prep: bf16 copies + transposes + column mean-squares (one read each)
    f2bf_kernel<<<(B * G) / 2048, 256, 0, stream>>>(images, img_bf, B * G);
    prep_kernel<<<dim3(K / 32, G / 32), 256, 0, stream>>>(
        xa, xa_bf, xaT_bf, c2a, G, K, 1.0f / (float)G);
    prep_kernel<<<dim3(K / 32, E / 32), 256, 0, stream>>>(
        xb, xb_bf, xbT_bf, c2b, E, K, 1.0f / (float)E);

    // encode (softmax eliminated): e = exp(images@xa*(2/G) - c2a), S_enc=rowsum
    float* S_enc = Svec;
    mfma_n64_kernel<EPI_U><<<dim3(K / 64, B / 128), 256, 0, stream>>>(
        img_bf, xaT_bf, e_bf, c2a, nullptr, S_enc, B, K, G, 2.0f / (float)G);

    // z0 = (e @ xb^T) / S_enc[row]   (== pik @ xb^T)
    mfma_z64_kernel<<<dim3(E / 64, B / 64), 256, 0, stream>>>(
        e_bf, xb_bf, z_bf, S_enc, B, E, K);

    // loop: fully fused steps, z updated in place, w never hits HBM
    for (int s = 0; s < N_STEP; ++s) {
        step_kernel<<<B / 64, 512, 0, stream>>>(
            z_bf, xbT_bf, xb_bf, e_bf, c2b);
    }

    // decode: x2 = mean(z^2) ; u = exp(z@xb*(2/E) - c2b) ; S0 = rowsum(u)
    float* S0 = Svec + B;
    rowmeansq_bf_kernel<<<B, 256, 0, stream>>>(z_bf, x2z);
    mfma_n64_kernel<EPI_U><<<dim3(K / 64, B / 128), 256, 0, stream>>>(
        z_bf, xbT_bf, wu_bf, c2b, nullptr, S0, B, K, E, 2.0f / (float)E);

    // loss: recon = (u @ xa^T)/D[row], D = P_NULL*e^{x2}+S0 ;
    // loss[b] = mean_g (recon - images)^2
    mfma_loss_kernel<<<dim3(G / 128, B / 128), 256, 0, stream>>>(
        wu_bf, xa_bf, out, x2z, images, S0, B, G, K);
}

// Round 4
// 446.991 us; speedup vs baseline: 1.9343x; 1.9343x over previous
//
#include <hip/hip_runtime.h>
#include <hip/hip_bf16.h>

// Problem constants (match reference)
constexpr int B = 8192;
constexpr int G = 1024;
constexpr int E = 256;
constexpr int K = 2048;
constexpr float P_NULL = 0.1f;
constexpr int N_STEP = 4;

typedef unsigned short u16;
typedef short bf16x8 __attribute__((ext_vector_type(8)));
typedef float f32x4 __attribute__((ext_vector_type(4)));

// raw-sync primitives (step kernel pipelining)
#define S_BARRIER __builtin_amdgcn_s_barrier()
#define SCHED0 __builtin_amdgcn_sched_barrier(0)
#define WAIT_VM0 asm volatile("s_waitcnt vmcnt(0)" ::: "memory")
#define WAIT_LGKM0 asm volatile("s_waitcnt lgkmcnt(0)" ::: "memory")

// ---------------------------------------------------------------------------
// bf16 <-> f32 (RNE)
// ---------------------------------------------------------------------------
__device__ inline u16 f2bf(float f) {
    union { float f; uint32_t u; } cv;
    cv.f = f;
    const uint32_t u = cv.u;
    return (u16)((u + 0x7fffu + ((u >> 16) & 1u)) >> 16);
}
__device__ inline float bf2f(u16 h) {
    union { uint32_t u; float f; } cv;
    cv.u = ((uint32_t)h) << 16;
    return cv.f;
}
__device__ inline uint4 pack8(const float* v) {
    uint4 u;
    u.x = (uint32_t)f2bf(v[0]) | ((uint32_t)f2bf(v[1]) << 16);
    u.y = (uint32_t)f2bf(v[2]) | ((uint32_t)f2bf(v[3]) << 16);
    u.z = (uint32_t)f2bf(v[4]) | ((uint32_t)f2bf(v[5]) << 16);
    u.w = (uint32_t)f2bf(v[6]) | ((uint32_t)f2bf(v[7]) << 16);
    return u;
}

// async global->LDS, 16B per lane (LDS dest is lane-linear; global src is
// per-lane and may be permuted -> XOR-swizzle is applied on the GLOBAL side)
typedef __attribute__((address_space(1))) const void* gaddr_t;
typedef __attribute__((address_space(3))) void* laddr_t;
__device__ inline void gload_lds16(const void* g, void* l) {
    __builtin_amdgcn_global_load_lds((gaddr_t)g, (laddr_t)l, 16, 0, 0);
}

// XCD-aware tile swizzle (requires gridDim.y % 8 == 0)
__device__ inline void swizzle_tiles(int& tr, int& tc) {
    const int cx = gridDim.x, cy = gridDim.y;
    const int id = blockIdx.y * cx + blockIdx.x;
    const int k = id & 7;
    const int q = id >> 3;
    tr = k * (cy >> 3) + q / cx;
    tc = q % cx;
}

// ---------------------------------------------------------------------------
// Reduction helpers (256-thread blocks, wave64)
// ---------------------------------------------------------------------------
__device__ inline float wave_sum(float v) {
#pragma unroll
    for (int off = 32; off > 0; off >>= 1) v += __shfl_down(v, off, 64);
    return v;
}
__device__ inline float block_sum256(float v, float* sm) {
    v = wave_sum(v);
    const int w = threadIdx.x >> 6;
    if ((threadIdx.x & 63) == 0) sm[w] = v;
    __syncthreads();
    const float r = sm[0] + sm[1] + sm[2] + sm[3];
    __syncthreads();
    return r;
}

// ---------------------------------------------------------------------------
// f32 -> bf16 flat convert, 8 elems/thread
// ---------------------------------------------------------------------------
__global__ __launch_bounds__(256) void f2bf_kernel(
    const float* __restrict__ in, u16* __restrict__ out, int n) {
    const int i = (blockIdx.x * 256 + threadIdx.x) * 8;
    if (i + 7 >= n) {
        for (int j = i; j < n; ++j) out[j] = f2bf(in[j]);
        return;
    }
    const float4 a = *(const float4*)(in + i);
    const float4 b = *(const float4*)(in + i + 4);
    float v[8] = {a.x, a.y, a.z, a.w, b.x, b.y, b.z, b.w};
    *(uint4*)(out + i) = pack8(v);
}

// ---------------------------------------------------------------------------
// Fused prep: f32 (R,C) -> bf16 (R,C) copy + bf16 (C,R) transpose +
// csq[c] += (1/R) sum_r v^2.  grid (C/32, R/32), block 256.
// ---------------------------------------------------------------------------
__global__ __launch_bounds__(256) void prep_kernel(
    const float* __restrict__ in, u16* __restrict__ outN,
    u16* __restrict__ outT, float* __restrict__ csq, int R, int C,
    float inv_R) {
    __shared__ float tile[32][33];
    __shared__ float sred[8][32];
    const int bx = blockIdx.x * 32, by = blockIdx.y * 32;
    const int x = threadIdx.x & 31, y0 = threadIdx.x >> 5;
    float s = 0.f;
#pragma unroll
    for (int yy = 0; yy < 32; yy += 8) {
        const float v = in[(size_t)(by + y0 + yy) * C + bx + x];
        tile[y0 + yy][x] = v;
        outN[(size_t)(by + y0 + yy) * C + bx + x] = f2bf(v);
        s = fmaf(v, v, s);
    }
    sred[y0][x] = s;
    __syncthreads();
#pragma unroll
    for (int yy = 0; yy < 32; yy += 8)
        outT[(size_t)(bx + y0 + yy) * R + by + x] = f2bf(tile[x][y0 + yy]);
    if (y0 == 0) {
        float t = 0.f;
#pragma unroll
        for (int k2 = 0; k2 < 8; ++k2) t += sred[k2][x];
        atomicAdd(csq + bx + x, t * inv_R);
    }
}

// ---------------------------------------------------------------------------
// MFMA bf16 GEMM, 128x64 tile (kept for encode/decode):
//   EPI_U: u = exp(alpha*acc - bias[col]) -> bf16 C; Saux[row] += row-sum
// ---------------------------------------------------------------------------
enum { EPI_U = 0, EPI_W = 1 };

template <int EPI>
__global__ __launch_bounds__(256) void mfma_n64_kernel(
    const u16* __restrict__ A, const u16* __restrict__ Bm,
    u16* __restrict__ C, const float* __restrict__ bias,
    const u16* __restrict__ Paux, float* __restrict__ Saux,
    int M, int N, int Kd, float alpha) {
    __shared__ u16 smem[12288];  // As 8192 (128x64) | Bs 4096 (64x64)
    u16* As = smem;
    u16* Bs = smem + 8192;
    const int tid = threadIdx.x;
    int btr, btc;
    swizzle_tiles(btr, btc);
    const int row0 = btr * 128, col0 = btc * 64;
    const int lane = tid & 63, wave = tid >> 6;
    const int wr = wave * 32;
    const int tx = lane & 15, quad = lane >> 4;
    const int txl = tx & 7;

    f32x4 acc[2][4] = {};

    for (int k0 = 0; k0 < Kd; k0 += 64) {
#pragma unroll
        for (int l = 0; l < 4; ++l) {
            const int lin = l * 2048 + tid * 8;
            const int r = lin >> 6;
            const int c = (((lin >> 3) & 7) ^ (r & 7)) * 8;  // XOR-swizzled src
            gload_lds16(A + (size_t)(row0 + r) * Kd + k0 + c, &As[lin]);
        }
#pragma unroll
        for (int l = 0; l < 2; ++l) {
            const int lin = l * 2048 + tid * 8;
            const int r = lin >> 6;
            const int c = (((lin >> 3) & 7) ^ (r & 7)) * 8;
            gload_lds16(Bm + (size_t)(col0 + r) * Kd + k0 + c, &Bs[lin]);
        }
        __syncthreads();
#pragma unroll
        for (int ks = 0; ks < 2; ++ks) {
            bf16x8 af[2], bfr[4];
            const int gsw = ((ks * 4 + quad) ^ txl) * 8;
#pragma unroll
            for (int i = 0; i < 2; ++i)
                af[i] = *(const bf16x8*)&As[(wr + i * 16 + tx) * 64 + gsw];
#pragma unroll
            for (int j = 0; j < 4; ++j)
                bfr[j] = *(const bf16x8*)&Bs[(j * 16 + tx) * 64 + gsw];
#pragma unroll
            for (int i = 0; i < 2; ++i)
#pragma unroll
                for (int j = 0; j < 4; ++j)
                    acc[i][j] = __builtin_amdgcn_mfma_f32_16x16x32_bf16(
                        af[i], bfr[j], acc[i][j], 0, 0, 0);
        }
        __syncthreads();
    }

    if (EPI == EPI_W) {
#pragma unroll
        for (int l = 0; l < 4; ++l) {
            const int lin = l * 2048 + tid * 8;
            const int r = lin >> 6;
            const int g = (lin >> 3) & 7;
            const int c = (g ^ (r & 7)) << 3;
            gload_lds16(Paux + (size_t)(row0 + r) * N + col0 + c, &smem[lin]);
        }
    }
    __syncthreads();

#pragma unroll
    for (int i = 0; i < 2; ++i) {
        float srow[4] = {0.f, 0.f, 0.f, 0.f};
#pragma unroll
        for (int j = 0; j < 4; ++j) {
            const int pcol = j * 16 + tx;
            const float cb = bias[col0 + pcol];
#pragma unroll
            for (int r = 0; r < 4; ++r) {
                const int prow = wr + i * 16 + quad * 4 + r;
                const int paddr = prow * 64 +
                    (((pcol >> 3) ^ (prow & 7)) << 3) + (pcol & 7);
                float v = __expf(fmaf(acc[i][j][r], alpha, -cb));
                if (EPI == EPI_W) v *= bf2f(smem[paddr]);
                srow[r] += v;
                smem[paddr] = f2bf(v);
            }
        }
#pragma unroll
        for (int r = 0; r < 4; ++r) {
            float s = srow[r];
            s += __shfl_xor(s, 1, 64);
            s += __shfl_xor(s, 2, 64);
            s += __shfl_xor(s, 4, 64);
            s += __shfl_xor(s, 8, 64);
            if (tx == 0)
                atomicAdd(&Saux[row0 + wr + i * 16 + quad * 4 + r], s);
        }
    }
    __syncthreads();

    const int rr = tid >> 1, hs = tid & 1;
#pragma unroll
    for (int u = 0; u < 4; ++u) {
        const int gl = hs * 4 + u;
        const int pg = gl ^ (rr & 7);
        *(uint4*)(C + (size_t)(row0 + rr) * N + col0 + gl * 8) =
            *(const uint4*)&smem[rr * 64 + pg * 8];
    }
}

// ---------------------------------------------------------------------------
// MFMA bf16 GEMM, 64x64 tile, for z0 = (e @ xb^T) / S_enc[row].
// ---------------------------------------------------------------------------
__global__ __launch_bounds__(256) void mfma_z64_kernel(
    const u16* __restrict__ A, const u16* __restrict__ Bm,
    u16* __restrict__ C, const float* __restrict__ Srow,
    int M, int N, int Kd) {
    __shared__ u16 As[64 * 64];
    __shared__ u16 Bs[64 * 64];
    const int tid = threadIdx.x;
    int btr, btc;
    swizzle_tiles(btr, btc);
    const int row0 = btr * 64, col0 = btc * 64;
    const int lane = tid & 63, wave = tid >> 6;
    const int wr = (wave >> 1) * 32, wc = (wave & 1) * 32;
    const int tx = lane & 15, quad = lane >> 4;
    const int txl = tx & 7;

    f32x4 acc[2][2] = {};

    for (int k0 = 0; k0 < Kd; k0 += 64) {
#pragma unroll
        for (int l = 0; l < 2; ++l) {
            const int lin = l * 2048 + tid * 8;
            const int r = lin >> 6;
            const int c = (((lin >> 3) & 7) ^ (r & 7)) * 8;
            gload_lds16(A + (size_t)(row0 + r) * Kd + k0 + c, &As[lin]);
        }
#pragma unroll
        for (int l = 0; l < 2; ++l) {
            const int lin = l * 2048 + tid * 8;
            const int r = lin >> 6;
            const int c = (((lin >> 3) & 7) ^ (r & 7)) * 8;
            gload_lds16(Bm + (size_t)(col0 + r) * Kd + k0 + c, &Bs[lin]);
        }
        __syncthreads();
#pragma unroll
        for (int ks = 0; ks < 2; ++ks) {
            bf16x8 af[2], bfr[2];
            const int gsw = ((ks * 4 + quad) ^ txl) * 8;
#pragma unroll
            for (int i = 0; i < 2; ++i)
                af[i] = *(const bf16x8*)&As[(wr + i * 16 + tx) * 64 + gsw];
#pragma unroll
            for (int j = 0; j < 2; ++j)
                bfr[j] = *(const bf16x8*)&Bs[(wc + j * 16 + tx) * 64 + gsw];
#pragma unroll
            for (int i = 0; i < 2; ++i)
#pragma unroll
                for (int j = 0; j < 2; ++j)
                    acc[i][j] = __builtin_amdgcn_mfma_f32_16x16x32_bf16(
                        af[i], bfr[j], acc[i][j], 0, 0, 0);
        }
        __syncthreads();
    }

#pragma unroll
    for (int i = 0; i < 2; ++i)
#pragma unroll
        for (int r = 0; r < 4; ++r) {
            const int row = row0 + wr + i * 16 + quad * 4 + r;
            const float sc = Srow ? (1.0f / Srow[row]) : 1.0f;
#pragma unroll
            for (int j = 0; j < 2; ++j) {
                const int col = col0 + wc + j * 16 + tx;
                C[(size_t)row * N + col] = f2bf(acc[i][j][r] * sc);
            }
        }
}

// ---------------------------------------------------------------------------
// STEP, R4: K-split partial kernel.
// Model (R0-R2): bottleneck is per-CU VMEM ingest (~15 B/cy); per-CU bytes =
// (B/rows_per_block) * working_set / 256 -> depends ONLY on rows/block.
// Fix: 128 rows/block x K-split P=4 -> grid 256 (1/CU), per-CU ingest
// 2.3MB -> ~0.84MB. Blocks write f32 z' partials Zp[4][B][E] + Sw partials
// Sp[4][B]; norm_kernel sums parts, divides, writes z bf16.
// 8 waves (wh=32-row band x wk=k/e-half). Chunk = 32 k's, 16 chunks.
//   t-part: wave computes t[band][kcol=wk*16+tx] (contraction e=256, 8 s-steps)
//   epilogue: w = e*exp(t*ascale - c2b) -> ws (LDS, padded 40)
//   z-part: acc2[band][e=wk*128..] += w @ xbT  (1 k-frag/chunk)
// LDS: region A (xbT chunk dbuf 32KB + xb chunk dbuf 32KB; prologue z-band
// 64KB overlays it) + es dbuf 20KB + ws 10KB = ~95KB, 1 block/CU.
// part = bid&3: round-robin XCD dispatch puts ONE part per XCD -> each XCD's
// L2 holds only its 512KB xb k-slice.
// ---------------------------------------------------------------------------
constexpr int XBTS0 = 0;          // [32k][256e] granule-XOR8
constexpr int XBTS1 = 8192;
constexpr int XBS0 = 16384;       // [256e][32k] granule-XOR4 (involution)
constexpr int XBS1 = 24576;
constexpr int ES0 = 32768;        // [128r][40k-padded]
constexpr int ES1 = 37888;
constexpr int WSO = 43008;        // [128r][40k-padded]
constexpr int SMEM_U16 = 48128;

__global__ __launch_bounds__(512, 2) void step_part_kernel(
    const u16* __restrict__ Z,      // (B,E) current z
    const u16* __restrict__ XbT,    // (K,E)
    const u16* __restrict__ Xb,     // (E,K)
    const u16* __restrict__ Ebf,    // (B,K) unnormalized encode weights
    const float* __restrict__ c2b,  // (K)
    float* __restrict__ Zp,         // (4,B,E) f32 partials
    float* __restrict__ Sp) {       // (4,B) f32 partials
    __shared__ u16 smem[SMEM_U16];
    __shared__ float redS[2][128];
    const int tid = threadIdx.x;
    const int lane = tid & 63, wave = tid >> 6;
    const int wh = wave >> 1, wk = wave & 1;  // 32-row band, k/e-half
    const int tx = lane & 15, quad = lane >> 4;
    const int part = blockIdx.x & 3;
    const int row0 = (blockIdx.x >> 2) * 128;
    const int kbase = part * 512;
    const float ascale = 2.0f / (float)E;
    const int kcol = wk * 16 + tx;            // lane's k-col in chunk (0..31)
    const int erow_ = tid >> 2;               // e stage: row (0..127)
    const int eg_ = tid & 3;                  // e stage: 8-col group
    const int ewaddr = erow_ * 40 + eg_ * 8;  // padded es/ws row stride 40 u16

    // ---- prologue: z band -> region A ([128r][256e], granule-XOR8) ----
#pragma unroll
    for (int l = 0; l < 8; ++l) {
        const int lin = l * 4096 + tid * 8;
        const int r = lin >> 8, gf = (lin >> 3) & 31;
        const int eoff = ((gf & 24) | ((gf & 7) ^ (r & 7))) << 3;
        gload_lds16(Z + (size_t)(row0 + r) * E + eoff, &smem[lin]);
    }
    // e chunk 0 -> regs ; cb
    uint4 ereg = *(const uint4*)&Ebf[(size_t)(row0 + erow_) * K + kbase + eg_ * 8];
    float cb = c2b[kbase + kcol];
    WAIT_VM0;
    SCHED0;
    S_BARRIER;
    SCHED0;

    // z A-frags: af[i][s] = z[wh*32+i*16+tx][e = s*32+quad*8 ..]
    bf16x8 af[2][8];
#pragma unroll
    for (int i = 0; i < 2; ++i) {
        const int row = wh * 32 + i * 16 + tx;
#pragma unroll
        for (int s = 0; s < 8; ++s) {
            const int g = s * 4 + quad;
            const int gp = (g & 24) | ((g & 7) ^ (row & 7));
            af[i][s] = *(const bf16x8*)&smem[row * 256 + gp * 8];
        }
    }
    // es[0] write (region separate from A)
    *(uint4*)&smem[ES0 + ewaddr] = ereg;
    WAIT_LGKM0;  // af reads + es0 write done before region A is overwritten
    SCHED0;
    S_BARRIER;
    SCHED0;

    // stage chunk 0 into buffers 0
#pragma unroll
    for (int l = 0; l < 2; ++l) {
        const int lin = l * 4096 + tid * 8;
        const int r = lin >> 8, gf = (lin >> 3) & 31;
        const int eoff = ((gf & 24) | ((gf & 7) ^ (r & 7))) << 3;
        gload_lds16(XbT + (size_t)(kbase + r) * E + eoff, &smem[XBTS0 + lin]);
    }
#pragma unroll
    for (int l = 0; l < 2; ++l) {
        const int lin = l * 4096 + tid * 8;
        const int e = lin >> 5, gq = (lin >> 3) & 3;
        const int koff = (gq ^ (e & 3) ^ ((e >> 2) & 3)) << 3;
        gload_lds16(Xb + (size_t)e * K + kbase + koff, &smem[XBS0 + lin]);
    }
    WAIT_VM0;
    SCHED0;
    S_BARRIER;
    SCHED0;

    f32x4 acc2[2][8] = {};  // z' partial acc: [row-half i][e-frag f]
    float srow[2][4] = {};  // Sw partials

    for (int kc = 0; kc < 16; ++kc) {
        const int p = kc & 1;
        const int xbtsP = p ? XBTS1 : XBTS0;
        const int xbsP = p ? XBS1 : XBS0;
        float cbn = 0.f;
        // ---- 1. stage chunk kc+1 (4 gload_lds) + e kc+1 (reg) ----
        if (kc < 15) {
            const int kn0 = kbase + (kc + 1) * 32;
            const int xbtsN = p ? XBTS0 : XBTS1;
            const int xbsN = p ? XBS0 : XBS1;
#pragma unroll
            for (int l = 0; l < 2; ++l) {
                const int lin = l * 4096 + tid * 8;
                const int r = lin >> 8, gf = (lin >> 3) & 31;
                const int eoff = ((gf & 24) | ((gf & 7) ^ (r & 7))) << 3;
                gload_lds16(XbT + (size_t)(kn0 + r) * E + eoff,
                            &smem[xbtsN + lin]);
            }
#pragma unroll
            for (int l = 0; l < 2; ++l) {
                const int lin = l * 4096 + tid * 8;
                const int e = lin >> 5, gq = (lin >> 3) & 3;
                const int koff = (gq ^ (e & 3) ^ ((e >> 2) & 3)) << 3;
                gload_lds16(Xb + (size_t)e * K + kn0 + koff,
                            &smem[xbsN + lin]);
            }
            ereg = *(const uint4*)&Ebf[(size_t)(row0 + erow_) * K + kn0 + eg_ * 8];
            cbn = c2b[kn0 + kcol];
        }
        SCHED0;  // pin stage issue above compute

        // ---- 2. t-part: ta[i] = z(band rows) @ xbT(k-col = kcol) ----
        bf16x8 bfr[8];
#pragma unroll
        for (int s = 0; s < 8; ++s) {
            const int g = s * 4 + quad;
            const int gp = (g & 24) | ((g & 7) ^ (kcol & 7));
            bfr[s] = *(const bf16x8*)&smem[xbtsP + kcol * 256 + gp * 8];
        }
        f32x4 ta[2] = {};
#pragma unroll
        for (int s = 0; s < 8; ++s)
#pragma unroll
            for (int i = 0; i < 2; ++i)
                ta[i] = __builtin_amdgcn_mfma_f32_16x16x32_bf16(
                    af[i][s], bfr[s], ta[i], 0, 0, 0);

        // ---- 3. epilogue: w = e * exp(t*ascale - cb) -> ws; Sw partial ----
        const int esP = p ? ES1 : ES0;
#pragma unroll
        for (int i = 0; i < 2; ++i)
#pragma unroll
            for (int r = 0; r < 4; ++r) {
                const int prow = wh * 32 + i * 16 + quad * 4 + r;
                const int paddr = prow * 40 + kcol;
                const float ev = bf2f(smem[esP + paddr]);
                const float wv = ev * __expf(fmaf(ta[i][r], ascale, -cb));
                srow[i][r] += wv;
                smem[WSO + paddr] = f2bf(wv);
            }
        // ---- B1: ws visible cross-wave (k-halves); vm loads in flight ----
        WAIT_LGKM0;
        SCHED0;
        S_BARRIER;
        SCHED0;

        // ---- 4. z-part: acc2 += w(band, 32k) @ xbT(32k, e=wk*128..) ----
        bf16x8 a2[2];
#pragma unroll
        for (int i = 0; i < 2; ++i) {
            const int row = wh * 32 + i * 16 + tx;
            a2[i] = *(const bf16x8*)&smem[WSO + row * 40 + quad * 8];
        }
#pragma unroll
        for (int f = 0; f < 8; ++f) {
            const int ecol = wk * 128 + f * 16 + tx;
            const int gq = quad ^ (ecol & 3) ^ ((ecol >> 2) & 3);
            const bf16x8 b2 = *(const bf16x8*)&smem[xbsP + ecol * 32 + gq * 8];
#pragma unroll
            for (int i = 0; i < 2; ++i)
                acc2[i][f] = __builtin_amdgcn_mfma_f32_16x16x32_bf16(
                    a2[i], b2, acc2[i][f], 0, 0, 0);
        }
        // ---- 5. es(kc+1) write (compiler waits vmcnt for ereg) ----
        if (kc < 15) {
            const int esN = p ? ES0 : ES1;
            *(uint4*)&smem[esN + ewaddr] = ereg;
        }
        cb = cbn;
        // ---- B2: chunk kc+1 staged + es write visible; dbuf swap safe ----
        WAIT_LGKM0;
        SCHED0;
        WAIT_VM0;
        S_BARRIER;
        SCHED0;
    }

    // ---- Sw partials: reduce over tx, combine wk-halves via LDS ----
#pragma unroll
    for (int i = 0; i < 2; ++i)
#pragma unroll
        for (int r = 0; r < 4; ++r) {
            float s = srow[i][r];
            s += __shfl_xor(s, 1, 64);
            s += __shfl_xor(s, 2, 64);
            s += __shfl_xor(s, 4, 64);
            s += __shfl_xor(s, 8, 64);
            if (tx == 0) redS[wk][wh * 32 + i * 16 + quad * 4 + r] = s;
        }
    __syncthreads();
    if (tid < 128)
        Sp[(size_t)part * B + row0 + tid] = redS[0][tid] + redS[1][tid];

    // ---- Zp stores: f32 partials, coalesced in tx ----
#pragma unroll
    for (int i = 0; i < 2; ++i)
#pragma unroll
        for (int f = 0; f < 8; ++f)
#pragma unroll
            for (int r = 0; r < 4; ++r) {
                const int row = wh * 32 + i * 16 + quad * 4 + r;
                const int e = wk * 128 + f * 16 + tx;
                Zp[((size_t)part * B + row0 + row) * E + e] = acc2[i][f][r];
            }
}

// ---------------------------------------------------------------------------
// norm: z[row][e] = (sum_p Zp[p][row][e]) / (sum_p Sp[p][row]) -> bf16
// grid B*E/2048 = 1024, block 256, 8 elems/thread.
// ---------------------------------------------------------------------------
__global__ __launch_bounds__(256) void norm_kernel(
    const float* __restrict__ Zp, const float* __restrict__ Sp,
    u16* __restrict__ Z) {
    const int gidx = blockIdx.x * 256 + threadIdx.x;
    const int row = gidx >> 5;
    const int e0 = (gidx & 31) * 8;
    const float s = Sp[row] + Sp[B + row] + Sp[2 * B + row] + Sp[3 * B + row];
    const float inv = 1.0f / s;
    const size_t base = (size_t)row * E + e0;
    float4 a0 = *(const float4*)(Zp + base);
    float4 a1 = *(const float4*)(Zp + base + 4);
#pragma unroll
    for (int p = 1; p < 4; ++p) {
        const float4 b0 = *(const float4*)(Zp + (size_t)p * B * E + base);
        const float4 b1 = *(const float4*)(Zp + (size_t)p * B * E + base + 4);
        a0.x += b0.x; a0.y += b0.y; a0.z += b0.z; a0.w += b0.w;
        a1.x += b1.x; a1.y += b1.y; a1.z += b1.z; a1.w += b1.w;
    }
    float v[8] = {a0.x * inv, a0.y * inv, a0.z * inv, a0.w * inv,
                  a1.x * inv, a1.y * inv, a1.z * inv, a1.w * inv};
    *(uint4*)(Z + base) = pack8(v);
}

// ---------------------------------------------------------------------------
// MFMA bf16 GEMM (128x128 tile) with fused MSE-loss epilogue:
// D = P_NULL*exp(x2[row]) + S0[row];
// loss[row] += (1/N)*sum_col (acc/D - X[row,col])^2
// ---------------------------------------------------------------------------
__global__ __launch_bounds__(256) void mfma_loss_kernel(
    const u16* __restrict__ A, const u16* __restrict__ Bm,
    float* __restrict__ loss, const float* __restrict__ x2,
    const float* __restrict__ X, const float* __restrict__ S0,
    int M, int N, int Kd) {
    __shared__ u16 As[128 * 64];
    __shared__ u16 Bs[128 * 64];
    const int tid = threadIdx.x;
    int btr, btc;
    swizzle_tiles(btr, btc);
    const int row0 = btr * 128, col0 = btc * 128;
    const int lane = tid & 63, wave = tid >> 6;
    const int wr = (wave >> 1) * 64, wc = (wave & 1) * 64;
    const int tx = lane & 15, quad = lane >> 4;
    const int txl = tx & 7;

    f32x4 acc[4][4] = {};

    for (int k0 = 0; k0 < Kd; k0 += 64) {
#pragma unroll
        for (int l = 0; l < 4; ++l) {
            const int lin = l * 2048 + tid * 8;
            const int r = lin >> 6;
            const int c = (((lin >> 3) & 7) ^ (r & 7)) * 8;
            gload_lds16(A + (size_t)(row0 + r) * Kd + k0 + c, &As[lin]);
        }
#pragma unroll
        for (int l = 0; l < 4; ++l) {
            const int lin = l * 2048 + tid * 8;
            const int r = lin >> 6;
            const int c = (((lin >> 3) & 7) ^ (r & 7)) * 8;
            gload_lds16(Bm + (size_t)(col0 + r) * Kd + k0 + c, &Bs[lin]);
        }
        __syncthreads();
#pragma unroll
        for (int ks = 0; ks < 2; ++ks) {
            bf16x8 af[4], bfr[4];
            const int gsw = ((ks * 4 + quad) ^ txl) * 8;
#pragma unroll
            for (int i = 0; i < 4; ++i)
                af[i] = *(const bf16x8*)&As[(wr + i * 16 + tx) * 64 + gsw];
#pragma unroll
            for (int j = 0; j < 4; ++j)
                bfr[j] = *(const bf16x8*)&Bs[(wc + j * 16 + tx) * 64 + gsw];
#pragma unroll
            for (int i = 0; i < 4; ++i)
#pragma unroll
                for (int j = 0; j < 4; ++j)
                    acc[i][j] = __builtin_amdgcn_mfma_f32_16x16x32_bf16(
                        af[i], bfr[j], acc[i][j], 0, 0, 0);
        }
        __syncthreads();
    }

    const float inv_n = 1.0f / (float)N;
#pragma unroll
    for (int i = 0; i < 4; ++i) {
#pragma unroll
        for (int r = 0; r < 4; ++r) {
            const int row = row0 + wr + i * 16 + quad * 4 + r;
            const float D = P_NULL * __expf(x2[row]) + S0[row];
            const float invD = 1.0f / D;
            float s = 0.f;
#pragma unroll
            for (int j = 0; j < 4; ++j) {
                const int col = col0 + wc + j * 16 + tx;
                const float d = acc[i][j][r] * invD - X[(size_t)row * N + col];
                s = fmaf(d, d, s);
            }
            s += __shfl_xor(s, 1, 64);
            s += __shfl_xor(s, 2, 64);
            s += __shfl_xor(s, 4, 64);
            s += __shfl_xor(s, 8, 64);
            if (tx == 0) atomicAdd(&loss[row], s * inv_n);
        }
    }
}

// ---------------------------------------------------------------------------
// Row mean of squares of Z (B,E) bf16: x2[row] = mean(Z[row,:]^2)
// ---------------------------------------------------------------------------
__global__ __launch_bounds__(256) void rowmeansq_bf_kernel(
    const u16* __restrict__ Z, float* __restrict__ out) {
    __shared__ float sm[4];
    const float v = bf2f(Z[(size_t)blockIdx.x * E + threadIdx.x]);
    const float s = block_sum256(v * v, sm);
    if (threadIdx.x == 0) out[blockIdx.x] = s * (1.0f / (float)E);
}

// ---------------------------------------------------------------------------
extern "C" void kernel_launch(void* const* d_in, const int* in_sizes, int n_in,
                              void* d_out, int out_size, void* d_ws, size_t ws_size,
                              hipStream_t stream) {
    const float* images = (const float*)d_in[0];  // (B,G)
    const float* xa     = (const float*)d_in[1];  // (G,K)
    const float* xb     = (const float*)d_in[2];  // (E,K)
    float* out = (float*)d_out;                   // (B,)

    // workspace carve-up (u16 elements, all regions 16B-aligned)
    u16* img_bf = (u16*)d_ws;                      // B*G
    u16* xa_bf  = img_bf + (size_t)B * G;          // G*K
    u16* xaT_bf = xa_bf + (size_t)G * K;           // K*G
    u16* xb_bf  = xaT_bf + (size_t)K * G;          // E*K
    u16* xbT_bf = xb_bf + (size_t)E * K;           // K*E
    u16* e_bf   = xbT_bf + (size_t)K * E;          // B*K (unnormalized enc e)
    u16* wu_bf  = e_bf + (size_t)B * K;            // B*K (decode u)
    u16* z_bf   = wu_bf + (size_t)B * K;           // B*E
    float* c2a  = (float*)(z_bf + (size_t)B * E);  // K   --+ one memset
    float* c2b  = c2a + K;                         // K     |
    float* Svec = c2b + K;                         // 2*B --+ (S_enc, S0)
    float* x2z  = Svec + 2 * B;                    // B (fully written)
    float* Sp   = x2z + B;                         // 4*B (fully written/step)
    // Zp (4,B,E) f32 = 32MB overlays wu_bf (B*K u16 = 32MB; wu only used
    // in decode, after the step loop).
    float* Zp = (float*)wu_bf;

    (void)hipMemsetAsync(d_out, 0, (size_t)B * sizeof(float), stream);
    (void)hipMemsetAsync(c2a, 0, (size_t)(2 * K + 2 * B) * sizeof(float), stream);

    // prep: bf16 copies + transposes + column mean-squares (one read each)
    f2bf_kernel<<<(B * G) / 2048, 256, 0, stream>>>(images, img_bf, B * G);
    prep_kernel<<<dim3(K / 32, G / 32), 256, 0, stream>>>(
        xa, xa_bf, xaT_bf, c2a, G, K, 1.0f / (float)G);
    prep_kernel<<<dim3(K / 32, E / 32), 256, 0, stream>>>(
        xb, xb_bf, xbT_bf, c2b, E, K, 1.0f / (float)E);

    // encode (softmax eliminated): e = exp(images@xa*(2/G) - c2a), S_enc=rowsum
    float* S_enc = Svec;
    mfma_n64_kernel<EPI_U><<<dim3(K / 64, B / 128), 256, 0, stream>>>(
        img_bf, xaT_bf, e_bf, c2a, nullptr, S_enc, B, K, G, 2.0f / (float)G);

    // z0 = (e @ xb^T) / S_enc[row]   (== pik @ xb^T)
    mfma_z64_kernel<<<dim3(E / 64, B / 64), 256, 0, stream>>>(
        e_bf, xb_bf, z_bf, S_enc, B, E, K);

    // loop: K-split partial steps + normalize (w never hits HBM)
    for (int s = 0; s < N_STEP; ++s) {
        step_part_kernel<<<256, 512, 0, stream>>>(
            z_bf, xbT_bf, xb_bf, e_bf, c2b, Zp, Sp);
        norm_kernel<<<(B * E) / 2048, 256, 0, stream>>>(Zp, Sp, z_bf);
    }

    // decode: x2 = mean(z^2) ; u = exp(z@xb*(2/E) - c2b) ; S0 = rowsum(u)
    float* S0 = Svec + B;
    rowmeansq_bf_kernel<<<B, 256, 0, stream>>>(z_bf, x2z);
    mfma_n64_kernel<EPI_U><<<dim3(K / 64, B / 128), 256, 0, stream>>>(
        z_bf, xbT_bf, wu_bf, c2b, nullptr, S0, B, K, E, 2.0f / (float)E);

    // loss: recon = (u @ xa^T)/D[row], D = P_NULL*e^{x2}+S0 ;
    // loss[b] = mean_g (recon - images)^2
    mfma_loss_kernel<<<dim3(G / 128, B / 128), 256, 0, stream>>>(
        wu_bf, xa_bf, out, x2z, images, S0, B, G, K);
}

// Round 5
// 440.074 us; speedup vs baseline: 1.9647x; 1.0157x over previous
//
#include <hip/hip_runtime.h>
#include <hip/hip_bf16.h>

// Problem constants (match reference)
constexpr int B = 8192;
constexpr int G = 1024;
constexpr int E = 256;
constexpr int K = 2048;
constexpr float P_NULL = 0.1f;
constexpr int N_STEP = 4;

typedef unsigned short u16;
typedef short bf16x8 __attribute__((ext_vector_type(8)));
typedef float f32x4 __attribute__((ext_vector_type(4)));

// raw-sync primitives (step kernel pipelining)
#define S_BARRIER __builtin_amdgcn_s_barrier()
#define SCHED0 __builtin_amdgcn_sched_barrier(0)
#define WAIT_VM0 asm volatile("s_waitcnt vmcnt(0)" ::: "memory")
#define WAIT_LGKM0 asm volatile("s_waitcnt lgkmcnt(0)" ::: "memory")

// ---------------------------------------------------------------------------
// bf16 <-> f32 (RNE)
// ---------------------------------------------------------------------------
__device__ inline u16 f2bf(float f) {
    union { float f; uint32_t u; } cv;
    cv.f = f;
    const uint32_t u = cv.u;
    return (u16)((u + 0x7fffu + ((u >> 16) & 1u)) >> 16);
}
__device__ inline float bf2f(u16 h) {
    union { uint32_t u; float f; } cv;
    cv.u = ((uint32_t)h) << 16;
    return cv.f;
}
__device__ inline uint4 pack8(const float* v) {
    uint4 u;
    u.x = (uint32_t)f2bf(v[0]) | ((uint32_t)f2bf(v[1]) << 16);
    u.y = (uint32_t)f2bf(v[2]) | ((uint32_t)f2bf(v[3]) << 16);
    u.z = (uint32_t)f2bf(v[4]) | ((uint32_t)f2bf(v[5]) << 16);
    u.w = (uint32_t)f2bf(v[6]) | ((uint32_t)f2bf(v[7]) << 16);
    return u;
}

// async global->LDS, 16B per lane (LDS dest is lane-linear; global src is
// per-lane and may be permuted -> XOR-swizzle is applied on the GLOBAL side)
typedef __attribute__((address_space(1))) const void* gaddr_t;
typedef __attribute__((address_space(3))) void* laddr_t;
__device__ inline void gload_lds16(const void* g, void* l) {
    __builtin_amdgcn_global_load_lds((gaddr_t)g, (laddr_t)l, 16, 0, 0);
}

// XCD-aware tile swizzle (requires gridDim.y % 8 == 0)
__device__ inline void swizzle_tiles(int& tr, int& tc) {
    const int cx = gridDim.x, cy = gridDim.y;
    const int id = blockIdx.y * cx + blockIdx.x;
    const int k = id & 7;
    const int q = id >> 3;
    tr = k * (cy >> 3) + q / cx;
    tc = q % cx;
}

// ---------------------------------------------------------------------------
// Reduction helpers (256-thread blocks, wave64)
// ---------------------------------------------------------------------------
__device__ inline float wave_sum(float v) {
#pragma unroll
    for (int off = 32; off > 0; off >>= 1) v += __shfl_down(v, off, 64);
    return v;
}
__device__ inline float block_sum256(float v, float* sm) {
    v = wave_sum(v);
    const int w = threadIdx.x >> 6;
    if ((threadIdx.x & 63) == 0) sm[w] = v;
    __syncthreads();
    const float r = sm[0] + sm[1] + sm[2] + sm[3];
    __syncthreads();
    return r;
}

// ---------------------------------------------------------------------------
// f32 -> bf16 flat convert, 8 elems/thread
// ---------------------------------------------------------------------------
__global__ __launch_bounds__(256) void f2bf_kernel(
    const float* __restrict__ in, u16* __restrict__ out, int n) {
    const int i = (blockIdx.x * 256 + threadIdx.x) * 8;
    if (i + 7 >= n) {
        for (int j = i; j < n; ++j) out[j] = f2bf(in[j]);
        return;
    }
    const float4 a = *(const float4*)(in + i);
    const float4 b = *(const float4*)(in + i + 4);
    float v[8] = {a.x, a.y, a.z, a.w, b.x, b.y, b.z, b.w};
    *(uint4*)(out + i) = pack8(v);
}

// ---------------------------------------------------------------------------
// Fused prep: f32 (R,C) -> bf16 (R,C) copy + bf16 (C,R) transpose +
// csq[c] += (1/R) sum_r v^2.  grid (C/32, R/32), block 256.
// ---------------------------------------------------------------------------
__global__ __launch_bounds__(256) void prep_kernel(
    const float* __restrict__ in, u16* __restrict__ outN,
    u16* __restrict__ outT, float* __restrict__ csq, int R, int C,
    float inv_R) {
    __shared__ float tile[32][33];
    __shared__ float sred[8][32];
    const int bx = blockIdx.x * 32, by = blockIdx.y * 32;
    const int x = threadIdx.x & 31, y0 = threadIdx.x >> 5;
    float s = 0.f;
#pragma unroll
    for (int yy = 0; yy < 32; yy += 8) {
        const float v = in[(size_t)(by + y0 + yy) * C + bx + x];
        tile[y0 + yy][x] = v;
        outN[(size_t)(by + y0 + yy) * C + bx + x] = f2bf(v);
        s = fmaf(v, v, s);
    }
    sred[y0][x] = s;
    __syncthreads();
#pragma unroll
    for (int yy = 0; yy < 32; yy += 8)
        outT[(size_t)(bx + y0 + yy) * R + by + x] = f2bf(tile[x][y0 + yy]);
    if (y0 == 0) {
        float t = 0.f;
#pragma unroll
        for (int k2 = 0; k2 < 8; ++k2) t += sred[k2][x];
        atomicAdd(csq + bx + x, t * inv_R);
    }
}

// ---------------------------------------------------------------------------
// MFMA bf16 GEMM, 256x128 tile, 512 threads (R5, encode/decode):
// u = exp(alpha*acc - bias[col]) -> bf16 C; Saux[row] += row-sum.
// R4 post-mortem: 128x64 tile re-streams A 32x + B 64x = 768MB L2 ingest
// at ~12.8TB/s = the measured 60us (MfmaUtil 22% == 573TF/2.5PF checks).
// 256x128 -> A x16 + B x32 = 384MB (2x less). 8 waves (4 row-bands x 2
// col-halves), 64x64 out/wave (acc[4][4], same per-wave budget as the
// proven mfma_loss). LDS: 48KB staging, 64KB epilogue roundtrip ->
// 2 blocks/CU if VGPR<=128. launch_bounds(512,2): VGPR cap 256, NO spill
// (R3 lesson: spill = disaster; let occupancy float).
// ---------------------------------------------------------------------------
__global__ __launch_bounds__(512, 2) void mfma_big_kernel(
    const u16* __restrict__ A, const u16* __restrict__ Bm,
    u16* __restrict__ C, const float* __restrict__ bias,
    float* __restrict__ Saux, int M, int N, int Kd, float alpha) {
    __shared__ u16 smem[32768];  // loop: As 16384 u16 | Bs 8192 u16; epi: all
    u16* As = smem;
    u16* Bs = smem + 16384;
    const int tid = threadIdx.x;
    int btr, btc;
    swizzle_tiles(btr, btc);
    const int row0 = btr * 256, col0 = btc * 128;
    const int lane = tid & 63, wave = tid >> 6;
    const int wr = wave >> 1, wc = wave & 1;  // row-band (0..3), col-half
    const int tx = lane & 15, quad = lane >> 4;
    const int txl = tx & 7;

    f32x4 acc[4][4] = {};

    for (int k0 = 0; k0 < Kd; k0 += 64) {
#pragma unroll
        for (int l = 0; l < 4; ++l) {
            const int lin = l * 4096 + tid * 8;
            const int r = lin >> 6;
            const int c = (((lin >> 3) & 7) ^ (r & 7)) * 8;  // XOR-swizzled src
            gload_lds16(A + (size_t)(row0 + r) * Kd + k0 + c, &As[lin]);
        }
#pragma unroll
        for (int l = 0; l < 2; ++l) {
            const int lin = l * 4096 + tid * 8;
            const int r = lin >> 6;
            const int c = (((lin >> 3) & 7) ^ (r & 7)) * 8;
            gload_lds16(Bm + (size_t)(col0 + r) * Kd + k0 + c, &Bs[lin]);
        }
        __syncthreads();
#pragma unroll
        for (int ks = 0; ks < 2; ++ks) {
            bf16x8 af[4], bfr[4];
            const int gsw = ((ks * 4 + quad) ^ txl) * 8;
#pragma unroll
            for (int i = 0; i < 4; ++i)
                af[i] = *(const bf16x8*)&As[(wr * 64 + i * 16 + tx) * 64 + gsw];
#pragma unroll
            for (int j = 0; j < 4; ++j)
                bfr[j] = *(const bf16x8*)&Bs[(wc * 64 + j * 16 + tx) * 64 + gsw];
#pragma unroll
            for (int i = 0; i < 4; ++i)
#pragma unroll
                for (int j = 0; j < 4; ++j)
                    acc[i][j] = __builtin_amdgcn_mfma_f32_16x16x32_bf16(
                        af[i], bfr[j], acc[i][j], 0, 0, 0);
        }
        __syncthreads();
    }

    // ---- epilogue: per-wave 64x64 patch at wave*4096 in LDS ----
    const int wbase = wave * 4096;
#pragma unroll
    for (int i = 0; i < 4; ++i) {
        float srow[4] = {0.f, 0.f, 0.f, 0.f};
#pragma unroll
        for (int j = 0; j < 4; ++j) {
            const int pcol = j * 16 + tx;
            const float cb = bias[col0 + wc * 64 + pcol];
#pragma unroll
            for (int r = 0; r < 4; ++r) {
                const int prow = i * 16 + quad * 4 + r;  // in-wave row 0..63
                const int paddr = wbase + prow * 64 +
                    (((pcol >> 3) ^ (prow & 7)) << 3) + (pcol & 7);
                const float v = __expf(fmaf(acc[i][j][r], alpha, -cb));
                srow[r] += v;
                smem[paddr] = f2bf(v);
            }
        }
#pragma unroll
        for (int r = 0; r < 4; ++r) {
            float s = srow[r];
            s += __shfl_xor(s, 1, 64);
            s += __shfl_xor(s, 2, 64);
            s += __shfl_xor(s, 4, 64);
            s += __shfl_xor(s, 8, 64);
            if (tx == 0)
                atomicAdd(&Saux[row0 + wr * 64 + i * 16 + quad * 4 + r], s);
        }
    }
    __syncthreads();

    // ---- write-out: row rr=tid>>1 (0..255), half hs (64 cols), coalesced ----
    const int rr = tid >> 1, hs = tid & 1;
#pragma unroll
    for (int u = 0; u < 8; ++u) {
        const int c = hs * 64 + u * 8;
        const int wv = (rr >> 6) * 2 + (c >> 6);  // source wave patch
        const int rl = rr & 63, cl = c & 63;
        const int pg = ((cl >> 3) ^ (rl & 7)) << 3;
        *(uint4*)(C + (size_t)(row0 + rr) * N + col0 + c) =
            *(const uint4*)&smem[wv * 4096 + rl * 64 + pg];
    }
}

// ---------------------------------------------------------------------------
// MFMA bf16 GEMM, 64x64 tile, for z0 = (e @ xb^T) / S_enc[row].
// ---------------------------------------------------------------------------
__global__ __launch_bounds__(256) void mfma_z64_kernel(
    const u16* __restrict__ A, const u16* __restrict__ Bm,
    u16* __restrict__ C, const float* __restrict__ Srow,
    int M, int N, int Kd) {
    __shared__ u16 As[64 * 64];
    __shared__ u16 Bs[64 * 64];
    const int tid = threadIdx.x;
    int btr, btc;
    swizzle_tiles(btr, btc);
    const int row0 = btr * 64, col0 = btc * 64;
    const int lane = tid & 63, wave = tid >> 6;
    const int wr = (wave >> 1) * 32, wc = (wave & 1) * 32;
    const int tx = lane & 15, quad = lane >> 4;
    const int txl = tx & 7;

    f32x4 acc[2][2] = {};

    for (int k0 = 0; k0 < Kd; k0 += 64) {
#pragma unroll
        for (int l = 0; l < 2; ++l) {
            const int lin = l * 2048 + tid * 8;
            const int r = lin >> 6;
            const int c = (((lin >> 3) & 7) ^ (r & 7)) * 8;
            gload_lds16(A + (size_t)(row0 + r) * Kd + k0 + c, &As[lin]);
        }
#pragma unroll
        for (int l = 0; l < 2; ++l) {
            const int lin = l * 2048 + tid * 8;
            const int r = lin >> 6;
            const int c = (((lin >> 3) & 7) ^ (r & 7)) * 8;
            gload_lds16(Bm + (size_t)(col0 + r) * Kd + k0 + c, &Bs[lin]);
        }
        __syncthreads();
#pragma unroll
        for (int ks = 0; ks < 2; ++ks) {
            bf16x8 af[2], bfr[2];
            const int gsw = ((ks * 4 + quad) ^ txl) * 8;
#pragma unroll
            for (int i = 0; i < 2; ++i)
                af[i] = *(const bf16x8*)&As[(wr + i * 16 + tx) * 64 + gsw];
#pragma unroll
            for (int j = 0; j < 2; ++j)
                bfr[j] = *(const bf16x8*)&Bs[(wc + j * 16 + tx) * 64 + gsw];
#pragma unroll
            for (int i = 0; i < 2; ++i)
#pragma unroll
                for (int j = 0; j < 2; ++j)
                    acc[i][j] = __builtin_amdgcn_mfma_f32_16x16x32_bf16(
                        af[i], bfr[j], acc[i][j], 0, 0, 0);
        }
        __syncthreads();
    }

#pragma unroll
    for (int i = 0; i < 2; ++i)
#pragma unroll
        for (int r = 0; r < 4; ++r) {
            const int row = row0 + wr + i * 16 + quad * 4 + r;
            const float sc = Srow ? (1.0f / Srow[row]) : 1.0f;
#pragma unroll
            for (int j = 0; j < 2; ++j) {
                const int col = col0 + wc + j * 16 + tx;
                C[(size_t)row * N + col] = f2bf(acc[i][j][r] * sc);
            }
        }
}

// ---------------------------------------------------------------------------
// STEP, R4 structure (kept): K-split partial kernel. 128 rows/block x P=4
// K-parts -> grid 256 (1/CU). Blocks write f32 z' partials Zp[4][B][E] +
// Sw partials Sp[4][B]; norm_kernel sums parts, divides, writes z bf16.
// ---------------------------------------------------------------------------
constexpr int XBTS0 = 0;          // [32k][256e] granule-XOR8
constexpr int XBTS1 = 8192;
constexpr int XBS0 = 16384;       // [256e][32k] granule-XOR4 (involution)
constexpr int XBS1 = 24576;
constexpr int ES0 = 32768;        // [128r][40k-padded]
constexpr int ES1 = 37888;
constexpr int WSO = 43008;        // [128r][40k-padded]
constexpr int SMEM_U16 = 48128;

__global__ __launch_bounds__(512, 2) void step_part_kernel(
    const u16* __restrict__ Z,      // (B,E) current z
    const u16* __restrict__ XbT,    // (K,E)
    const u16* __restrict__ Xb,     // (E,K)
    const u16* __restrict__ Ebf,    // (B,K) unnormalized encode weights
    const float* __restrict__ c2b,  // (K)
    float* __restrict__ Zp,         // (4,B,E) f32 partials
    float* __restrict__ Sp) {       // (4,B) f32 partials
    __shared__ u16 smem[SMEM_U16];
    __shared__ float redS[2][128];
    const int tid = threadIdx.x;
    const int lane = tid & 63, wave = tid >> 6;
    const int wh = wave >> 1, wk = wave & 1;  // 32-row band, k/e-half
    const int tx = lane & 15, quad = lane >> 4;
    const int part = blockIdx.x & 3;
    const int row0 = (blockIdx.x >> 2) * 128;
    const int kbase = part * 512;
    const float ascale = 2.0f / (float)E;
    const int kcol = wk * 16 + tx;            // lane's k-col in chunk (0..31)
    const int erow_ = tid >> 2;               // e stage: row (0..127)
    const int eg_ = tid & 3;                  // e stage: 8-col group
    const int ewaddr = erow_ * 40 + eg_ * 8;  // padded es/ws row stride 40 u16

    // ---- prologue: z band -> region A ([128r][256e], granule-XOR8) ----
#pragma unroll
    for (int l = 0; l < 8; ++l) {
        const int lin = l * 4096 + tid * 8;
        const int r = lin >> 8, gf = (lin >> 3) & 31;
        const int eoff = ((gf & 24) | ((gf & 7) ^ (r & 7))) << 3;
        gload_lds16(Z + (size_t)(row0 + r) * E + eoff, &smem[lin]);
    }
    // e chunk 0 -> regs ; cb
    uint4 ereg = *(const uint4*)&Ebf[(size_t)(row0 + erow_) * K + kbase + eg_ * 8];
    float cb = c2b[kbase + kcol];
    WAIT_VM0;
    SCHED0;
    S_BARRIER;
    SCHED0;

    // z A-frags: af[i][s] = z[wh*32+i*16+tx][e = s*32+quad*8 ..]
    bf16x8 af[2][8];
#pragma unroll
    for (int i = 0; i < 2; ++i) {
        const int row = wh * 32 + i * 16 + tx;
#pragma unroll
        for (int s = 0; s < 8; ++s) {
            const int g = s * 4 + quad;
            const int gp = (g & 24) | ((g & 7) ^ (row & 7));
            af[i][s] = *(const bf16x8*)&smem[row * 256 + gp * 8];
        }
    }
    // es[0] write (region separate from A)
    *(uint4*)&smem[ES0 + ewaddr] = ereg;
    WAIT_LGKM0;  // af reads + es0 write done before region A is overwritten
    SCHED0;
    S_BARRIER;
    SCHED0;

    // stage chunk 0 into buffers 0
#pragma unroll
    for (int l = 0; l < 2; ++l) {
        const int lin = l * 4096 + tid * 8;
        const int r = lin >> 8, gf = (lin >> 3) & 31;
        const int eoff = ((gf & 24) | ((gf & 7) ^ (r & 7))) << 3;
        gload_lds16(XbT + (size_t)(kbase + r) * E + eoff, &smem[XBTS0 + lin]);
    }
#pragma unroll
    for (int l = 0; l < 2; ++l) {
        const int lin = l * 4096 + tid * 8;
        const int e = lin >> 5, gq = (lin >> 3) & 3;
        const int koff = (gq ^ (e & 3) ^ ((e >> 2) & 3)) << 3;
        gload_lds16(Xb + (size_t)e * K + kbase + koff, &smem[XBS0 + lin]);
    }
    WAIT_VM0;
    SCHED0;
    S_BARRIER;
    SCHED0;

    f32x4 acc2[2][8] = {};  // z' partial acc: [row-half i][e-frag f]
    float srow[2][4] = {};  // Sw partials

    for (int kc = 0; kc < 16; ++kc) {
        const int p = kc & 1;
        const int xbtsP = p ? XBTS1 : XBTS0;
        const int xbsP = p ? XBS1 : XBS0;
        float cbn = 0.f;
        // ---- 1. stage chunk kc+1 (4 gload_lds) + e kc+1 (reg) ----
        if (kc < 15) {
            const int kn0 = kbase + (kc + 1) * 32;
            const int xbtsN = p ? XBTS0 : XBTS1;
            const int xbsN = p ? XBS0 : XBS1;
#pragma unroll
            for (int l = 0; l < 2; ++l) {
                const int lin = l * 4096 + tid * 8;
                const int r = lin >> 8, gf = (lin >> 3) & 31;
                const int eoff = ((gf & 24) | ((gf & 7) ^ (r & 7))) << 3;
                gload_lds16(XbT + (size_t)(kn0 + r) * E + eoff,
                            &smem[xbtsN + lin]);
            }
#pragma unroll
            for (int l = 0; l < 2; ++l) {
                const int lin = l * 4096 + tid * 8;
                const int e = lin >> 5, gq = (lin >> 3) & 3;
                const int koff = (gq ^ (e & 3) ^ ((e >> 2) & 3)) << 3;
                gload_lds16(Xb + (size_t)e * K + kn0 + koff,
                            &smem[xbsN + lin]);
            }
            ereg = *(const uint4*)&Ebf[(size_t)(row0 + erow_) * K + kn0 + eg_ * 8];
            cbn = c2b[kn0 + kcol];
        }
        SCHED0;  // pin stage issue above compute

        // ---- 2. t-part: ta[i] = z(band rows) @ xbT(k-col = kcol) ----
        bf16x8 bfr[8];
#pragma unroll
        for (int s = 0; s < 8; ++s) {
            const int g = s * 4 + quad;
            const int gp = (g & 24) | ((g & 7) ^ (kcol & 7));
            bfr[s] = *(const bf16x8*)&smem[xbtsP + kcol * 256 + gp * 8];
        }
        f32x4 ta[2] = {};
#pragma unroll
        for (int s = 0; s < 8; ++s)
#pragma unroll
            for (int i = 0; i < 2; ++i)
                ta[i] = __builtin_amdgcn_mfma_f32_16x16x32_bf16(
                    af[i][s], bfr[s], ta[i], 0, 0, 0);

        // ---- 3. epilogue: w = e * exp(t*ascale - cb) -> ws; Sw partial ----
        const int esP = p ? ES1 : ES0;
#pragma unroll
        for (int i = 0; i < 2; ++i)
#pragma unroll
            for (int r = 0; r < 4; ++r) {
                const int prow = wh * 32 + i * 16 + quad * 4 + r;
                const int paddr = prow * 40 + kcol;
                const float ev = bf2f(smem[esP + paddr]);
                const float wv = ev * __expf(fmaf(ta[i][r], ascale, -cb));
                srow[i][r] += wv;
                smem[WSO + paddr] = f2bf(wv);
            }
        // ---- B1: ws visible cross-wave (k-halves); vm loads in flight ----
        WAIT_LGKM0;
        SCHED0;
        S_BARRIER;
        SCHED0;

        // ---- 4. z-part: acc2 += w(band, 32k) @ xbT(32k, e=wk*128..) ----
        bf16x8 a2[2];
#pragma unroll
        for (int i = 0; i < 2; ++i) {
            const int row = wh * 32 + i * 16 + tx;
            a2[i] = *(const bf16x8*)&smem[WSO + row * 40 + quad * 8];
        }
#pragma unroll
        for (int f = 0; f < 8; ++f) {
            const int ecol = wk * 128 + f * 16 + tx;
            const int gq = quad ^ (ecol & 3) ^ ((ecol >> 2) & 3);
            const bf16x8 b2 = *(const bf16x8*)&smem[xbsP + ecol * 32 + gq * 8];
#pragma unroll
            for (int i = 0; i < 2; ++i)
                acc2[i][f] = __builtin_amdgcn_mfma_f32_16x16x32_bf16(
                    a2[i], b2, acc2[i][f], 0, 0, 0);
        }
        // ---- 5. es(kc+1) write (compiler waits vmcnt for ereg) ----
        if (kc < 15) {
            const int esN = p ? ES0 : ES1;
            *(uint4*)&smem[esN + ewaddr] = ereg;
        }
        cb = cbn;
        // ---- B2: chunk kc+1 staged + es write visible; dbuf swap safe ----
        WAIT_LGKM0;
        SCHED0;
        WAIT_VM0;
        S_BARRIER;
        SCHED0;
    }

    // ---- Sw partials: reduce over tx, combine wk-halves via LDS ----
#pragma unroll
    for (int i = 0; i < 2; ++i)
#pragma unroll
        for (int r = 0; r < 4; ++r) {
            float s = srow[i][r];
            s += __shfl_xor(s, 1, 64);
            s += __shfl_xor(s, 2, 64);
            s += __shfl_xor(s, 4, 64);
            s += __shfl_xor(s, 8, 64);
            if (tx == 0) redS[wk][wh * 32 + i * 16 + quad * 4 + r] = s;
        }
    __syncthreads();
    if (tid < 128)
        Sp[(size_t)part * B + row0 + tid] = redS[0][tid] + redS[1][tid];

    // ---- Zp stores: f32 partials, coalesced in tx ----
#pragma unroll
    for (int i = 0; i < 2; ++i)
#pragma unroll
        for (int f = 0; f < 8; ++f)
#pragma unroll
            for (int r = 0; r < 4; ++r) {
                const int row = wh * 32 + i * 16 + quad * 4 + r;
                const int e = wk * 128 + f * 16 + tx;
                Zp[((size_t)part * B + row0 + row) * E + e] = acc2[i][f][r];
            }
}

// ---------------------------------------------------------------------------
// norm: z[row][e] = (sum_p Zp[p][row][e]) / (sum_p Sp[p][row]) -> bf16
// grid B*E/2048 = 1024, block 256, 8 elems/thread.
// ---------------------------------------------------------------------------
__global__ __launch_bounds__(256) void norm_kernel(
    const float* __restrict__ Zp, const float* __restrict__ Sp,
    u16* __restrict__ Z) {
    const int gidx = blockIdx.x * 256 + threadIdx.x;
    const int row = gidx >> 5;
    const int e0 = (gidx & 31) * 8;
    const float s = Sp[row] + Sp[B + row] + Sp[2 * B + row] + Sp[3 * B + row];
    const float inv = 1.0f / s;
    const size_t base = (size_t)row * E + e0;
    float4 a0 = *(const float4*)(Zp + base);
    float4 a1 = *(const float4*)(Zp + base + 4);
#pragma unroll
    for (int p = 1; p < 4; ++p) {
        const float4 b0 = *(const float4*)(Zp + (size_t)p * B * E + base);
        const float4 b1 = *(const float4*)(Zp + (size_t)p * B * E + base + 4);
        a0.x += b0.x; a0.y += b0.y; a0.z += b0.z; a0.w += b0.w;
        a1.x += b1.x; a1.y += b1.y; a1.z += b1.z; a1.w += b1.w;
    }
    float v[8] = {a0.x * inv, a0.y * inv, a0.z * inv, a0.w * inv,
                  a1.x * inv, a1.y * inv, a1.z * inv, a1.w * inv};
    *(uint4*)(Z + base) = pack8(v);
}

// ---------------------------------------------------------------------------
// MFMA bf16 GEMM (128x128 tile) with fused MSE-loss epilogue:
// D = P_NULL*exp(x2[row]) + S0[row];
// loss[row] += (1/N)*sum_col (acc/D - X[row,col])^2
// ---------------------------------------------------------------------------
__global__ __launch_bounds__(256) void mfma_loss_kernel(
    const u16* __restrict__ A, const u16* __restrict__ Bm,
    float* __restrict__ loss, const float* __restrict__ x2,
    const float* __restrict__ X, const float* __restrict__ S0,
    int M, int N, int Kd) {
    __shared__ u16 As[128 * 64];
    __shared__ u16 Bs[128 * 64];
    const int tid = threadIdx.x;
    int btr, btc;
    swizzle_tiles(btr, btc);
    const int row0 = btr * 128, col0 = btc * 128;
    const int lane = tid & 63, wave = tid >> 6;
    const int wr = (wave >> 1) * 64, wc = (wave & 1) * 64;
    const int tx = lane & 15, quad = lane >> 4;
    const int txl = tx & 7;

    f32x4 acc[4][4] = {};

    for (int k0 = 0; k0 < Kd; k0 += 64) {
#pragma unroll
        for (int l = 0; l < 4; ++l) {
            const int lin = l * 2048 + tid * 8;
            const int r = lin >> 6;
            const int c = (((lin >> 3) & 7) ^ (r & 7)) * 8;
            gload_lds16(A + (size_t)(row0 + r) * Kd + k0 + c, &As[lin]);
        }
#pragma unroll
        for (int l = 0; l < 4; ++l) {
            const int lin = l * 2048 + tid * 8;
            const int r = lin >> 6;
            const int c = (((lin >> 3) & 7) ^ (r & 7)) * 8;
            gload_lds16(Bm + (size_t)(col0 + r) * Kd + k0 + c, &Bs[lin]);
        }
        __syncthreads();
#pragma unroll
        for (int ks = 0; ks < 2; ++ks) {
            bf16x8 af[4], bfr[4];
            const int gsw = ((ks * 4 + quad) ^ txl) * 8;
#pragma unroll
            for (int i = 0; i < 4; ++i)
                af[i] = *(const bf16x8*)&As[(wr + i * 16 + tx) * 64 + gsw];
#pragma unroll
            for (int j = 0; j < 4; ++j)
                bfr[j] = *(const bf16x8*)&Bs[(wc + j * 16 + tx) * 64 + gsw];
#pragma unroll
            for (int i = 0; i < 4; ++i)
#pragma unroll
                for (int j = 0; j < 4; ++j)
                    acc[i][j] = __builtin_amdgcn_mfma_f32_16x16x32_bf16(
                        af[i], bfr[j], acc[i][j], 0, 0, 0);
        }
        __syncthreads();
    }

    const float inv_n = 1.0f / (float)N;
#pragma unroll
    for (int i = 0; i < 4; ++i) {
#pragma unroll
        for (int r = 0; r < 4; ++r) {
            const int row = row0 + wr + i * 16 + quad * 4 + r;
            const float D = P_NULL * __expf(x2[row]) + S0[row];
            const float invD = 1.0f / D;
            float s = 0.f;
#pragma unroll
            for (int j = 0; j < 4; ++j) {
                const int col = col0 + wc + j * 16 + tx;
                const float d = acc[i][j][r] * invD - X[(size_t)row * N + col];
                s = fmaf(d, d, s);
            }
            s += __shfl_xor(s, 1, 64);
            s += __shfl_xor(s, 2, 64);
            s += __shfl_xor(s, 4, 64);
            s += __shfl_xor(s, 8, 64);
            if (tx == 0) atomicAdd(&loss[row], s * inv_n);
        }
    }
}

// ---------------------------------------------------------------------------
// Row mean of squares of Z (B,E) bf16: x2[row] = mean(Z[row,:]^2)
// ---------------------------------------------------------------------------
__global__ __launch_bounds__(256) void rowmeansq_bf_kernel(
    const u16* __restrict__ Z, float* __restrict__ out) {
    __shared__ float sm[4];
    const float v = bf2f(Z[(size_t)blockIdx.x * E + threadIdx.x]);
    const float s = block_sum256(v * v, sm);
    if (threadIdx.x == 0) out[blockIdx.x] = s * (1.0f / (float)E);
}

// ---------------------------------------------------------------------------
extern "C" void kernel_launch(void* const* d_in, const int* in_sizes, int n_in,
                              void* d_out, int out_size, void* d_ws, size_t ws_size,
                              hipStream_t stream) {
    const float* images = (const float*)d_in[0];  // (B,G)
    const float* xa     = (const float*)d_in[1];  // (G,K)
    const float* xb     = (const float*)d_in[2];  // (E,K)
    float* out = (float*)d_out;                   // (B,)

    // workspace carve-up (u16 elements, all regions 16B-aligned)
    u16* img_bf = (u16*)d_ws;                      // B*G
    u16* xa_bf  = img_bf + (size_t)B * G;          // G*K
    u16* xaT_bf = xa_bf + (size_t)G * K;           // K*G
    u16* xb_bf  = xaT_bf + (size_t)K * G;          // E*K
    u16* xbT_bf = xb_bf + (size_t)E * K;           // K*E
    u16* e_bf   = xbT_bf + (size_t)K * E;          // B*K (unnormalized enc e)
    u16* wu_bf  = e_bf + (size_t)B * K;            // B*K (decode u)
    u16* z_bf   = wu_bf + (size_t)B * K;           // B*E
    float* c2a  = (float*)(z_bf + (size_t)B * E);  // K   --+ one memset
    float* c2b  = c2a + K;                         // K     |
    float* Svec = c2b + K;                         // 2*B --+ (S_enc, S0)
    float* x2z  = Svec + 2 * B;                    // B (fully written)
    float* Sp   = x2z + B;                         // 4*B (fully written/step)
    // Zp (4,B,E) f32 = 32MB overlays wu_bf (B*K u16 = 32MB; wu only used
    // in decode, after the step loop).
    float* Zp = (float*)wu_bf;

    (void)hipMemsetAsync(d_out, 0, (size_t)B * sizeof(float), stream);
    (void)hipMemsetAsync(c2a, 0, (size_t)(2 * K + 2 * B) * sizeof(float), stream);

    // prep: bf16 copies + transposes + column mean-squares (one read each)
    f2bf_kernel<<<(B * G) / 2048, 256, 0, stream>>>(images, img_bf, B * G);
    prep_kernel<<<dim3(K / 32, G / 32), 256, 0, stream>>>(
        xa, xa_bf, xaT_bf, c2a, G, K, 1.0f / (float)G);
    prep_kernel<<<dim3(K / 32, E / 32), 256, 0, stream>>>(
        xb, xb_bf, xbT_bf, c2b, E, K, 1.0f / (float)E);

    // encode (softmax eliminated): e = exp(images@xa*(2/G) - c2a), S_enc=rowsum
    float* S_enc = Svec;
    mfma_big_kernel<<<dim3(K / 128, B / 256), 512, 0, stream>>>(
        img_bf, xaT_bf, e_bf, c2a, S_enc, B, K, G, 2.0f / (float)G);

    // z0 = (e @ xb^T) / S_enc[row]   (== pik @ xb^T)
    mfma_z64_kernel<<<dim3(E / 64, B / 64), 256, 0, stream>>>(
        e_bf, xb_bf, z_bf, S_enc, B, E, K);

    // loop: K-split partial steps + normalize (w never hits HBM)
    for (int s = 0; s < N_STEP; ++s) {
        step_part_kernel<<<256, 512, 0, stream>>>(
            z_bf, xbT_bf, xb_bf, e_bf, c2b, Zp, Sp);
        norm_kernel<<<(B * E) / 2048, 256, 0, stream>>>(Zp, Sp, z_bf);
    }

    // decode: x2 = mean(z^2) ; u = exp(z@xb*(2/E) - c2b) ; S0 = rowsum(u)
    float* S0 = Svec + B;
    rowmeansq_bf_kernel<<<B, 256, 0, stream>>>(z_bf, x2z);
    mfma_big_kernel<<<dim3(K / 128, B / 256), 512, 0, stream>>>(
        z_bf, xbT_bf, wu_bf, c2b, S0, B, K, E, 2.0f / (float)E);

    // loss: recon = (u @ xa^T)/D[row], D = P_NULL*e^{x2}+S0 ;
    // loss[b] = mean_g (recon - images)^2
    mfma_loss_kernel<<<dim3(G / 128, B / 128), 256, 0, stream>>>(
        wu_bf, xa_bf, out, x2z, images, S0, B, G, K);
}